// Round 4
// baseline (9659.513 us; speedup 1.0000x reference)
//
#include <hip/hip_runtime.h>
#include <hip/hip_bf16.h>
#include <hip/hip_fp16.h>

#define TT 2048
#define BB 16
#define DD 256
#define GG 1024   // 4U
#define UU 256

using f32x4  = __attribute__((ext_vector_type(4))) float;
using short8 = __attribute__((ext_vector_type(8))) short;
using f16x8  = __attribute__((ext_vector_type(8))) _Float16;
using u32x4  = __attribute__((ext_vector_type(4))) unsigned int;

static __device__ __forceinline__ unsigned short f2h_u(float f){
  _Float16 h = (_Float16)f;
  return __builtin_bit_cast(unsigned short, h);
}
static __device__ __forceinline__ float h2f(unsigned short u){
  return (float)__builtin_bit_cast(_Float16, u);
}
static __device__ __forceinline__ unsigned short f2bf_u(float f){
  __hip_bfloat16 b = __float2bfloat16(f);
  return __builtin_bit_cast(unsigned short, b);
}
static __device__ __forceinline__ float sigmoid_f(float x){
  return 1.0f / (1.0f + __expf(-x));
}
static __device__ __forceinline__ float tanh_f(float x){
  float ax = fabsf(x);
  float e  = __expf(2.0f*ax);          // overflow -> inf is fine: r -> 1
  float r  = 1.0f - 2.0f/(e + 1.0f);
  return copysignf(r, x);
}
static __device__ __forceinline__ f32x4 mfma16x16x32_f16(f16x8 a, f16x8 b, f32x4 c){
  return __builtin_amdgcn_mfma_f32_16x16x32_f16(a, b, c, 0, 0, 0);
}

// ---- converts -------------------------------------------------------------
__global__ __launch_bounds__(256) void cvt_x_kernel(const float* __restrict__ x,
                                                    unsigned short* __restrict__ xh){
  int gid = blockIdx.x*256 + threadIdx.x;          // 2,097,152 threads, 4 elems each
  const float4* xv = (const float4*)x;
  float4 v = xv[gid];
  unsigned int u0 = (unsigned int)f2bf_u(v.x) | ((unsigned int)f2bf_u(v.y) << 16);
  unsigned int u1 = (unsigned int)f2bf_u(v.z) | ((unsigned int)f2bf_u(v.w) << 16);
  ((uint2*)xh)[gid] = make_uint2(u0, u1);
}

// W [256][1024] f32 -> W^T bf16 [dir][1024][256]
__global__ __launch_bounds__(256) void cvt_wt_kernel(const float* __restrict__ Wf,
                                                     const float* __restrict__ Wb,
                                                     unsigned short* __restrict__ wt){
  int gid = blockIdx.x*256 + threadIdx.x;          // 2*1024*256 = 524288
  int d   = gid >> 18;
  int rem = gid & 262143;
  int n   = rem >> 8;
  int k   = rem & 255;
  const float* src = d ? Wb : Wf;
  wt[gid] = f2bf_u(src[k*GG + n]);
}

// R [256][1024] f32 -> R^T f16 [dir][1024 col][256 k]
__global__ __launch_bounds__(256) void cvt_rt_kernel(const float* __restrict__ Rf,
                                                     const float* __restrict__ Rb,
                                                     unsigned short* __restrict__ rt){
  int gid = blockIdx.x*256 + threadIdx.x;          // 2*1024*64 = 131072
  int d   = gid >> 16;
  int rem = gid & 65535;
  int col = rem >> 6;
  int k4  = (rem & 63) << 2;
  const float* src = d ? Rb : Rf;
  unsigned int u0 = (unsigned int)f2h_u(src[(k4+0)*GG + col]) |
                    ((unsigned int)f2h_u(src[(k4+1)*GG + col]) << 16);
  unsigned int u1 = (unsigned int)f2h_u(src[(k4+2)*GG + col]) |
                    ((unsigned int)f2h_u(src[(k4+3)*GG + col]) << 16);
  *(uint2*)(rt + ((size_t)d*1024 + col)*256 + k4) = make_uint2(u0, u1);
}

// ---- proj GEMM: M-tile = 16 batches x 8 timesteps; writes projT[t][col][16b]
__global__ __launch_bounds__(256) void gemm_projT(const unsigned short* __restrict__ Ah,  // xh bf16 [16][2048][256]
                                                  const unsigned short* __restrict__ BTh, // wt bf16 [1024][256], one dir
                                                  unsigned short* __restrict__ Cd,        // projT one dir [Tc][1024][16] f16
                                                  int xstart, int Tc){
  __shared__ __align__(16) unsigned short smem[18432];  // 36864 B
  unsigned short* sA = smem;             // [128][72]
  unsigned short* sB = smem + 9216;      // [128][72]
  unsigned short* sC = smem;             // [128][136] (reuses sA/sB)

  int mt  = blockIdx.x >> 3;             // time-tile (8 t per tile)
  int nt  = blockIdx.x & 7;              // col-tile (128 cols)
  int tid = threadIdx.x;

  const unsigned short* Bb = BTh + (size_t)nt*128*DD;

  int w = tid >> 6, lane = tid & 63, l15 = lane & 15, l4 = lane >> 4;
  int wm = w >> 1, wn = w & 1;

  f32x4 zero4 = {0.0f, 0.0f, 0.0f, 0.0f};
  f32x4 acc[4][4];
#pragma unroll
  for (int i = 0; i < 4; ++i)
#pragma unroll
    for (int j = 0; j < 4; ++j) acc[i][j] = zero4;

  for (int kt = 0; kt < 4; ++kt){
    __syncthreads();
#pragma unroll
    for (int i = 0; i < 4; ++i){
      int ch = tid + i*256;
      int r = ch >> 3, c8 = ch & 7;
      int bb = r >> 3, ti = r & 7;
      int tx = xstart + mt*8 + ti;       // both dirs: ascending x-rows from xstart
      *(uint4*)(sA + r*72 + c8*8) = *(const uint4*)(Ah + ((size_t)bb*TT + tx)*DD + kt*64 + c8*8);
      *(uint4*)(sB + r*72 + c8*8) = *(const uint4*)(Bb + (size_t)r*DD + kt*64 + c8*8);
    }
    __syncthreads();
#pragma unroll
    for (int ks = 0; ks < 2; ++ks){
      short8 a[4], b[4];
#pragma unroll
      for (int mf = 0; mf < 4; ++mf)
        a[mf] = *(const short8*)(sA + (wm*64 + mf*16 + l15)*72 + ks*32 + l4*8);
#pragma unroll
      for (int nf = 0; nf < 4; ++nf)
        b[nf] = *(const short8*)(sB + (wn*64 + nf*16 + l15)*72 + ks*32 + l4*8);
#pragma unroll
      for (int mf = 0; mf < 4; ++mf)
#pragma unroll
        for (int nf = 0; nf < 4; ++nf)
          acc[mf][nf] = __builtin_amdgcn_mfma_f32_16x16x32_bf16(a[mf], b[nf], acc[mf][nf], 0, 0, 0);
    }
  }
  __syncthreads();
#pragma unroll
  for (int mf = 0; mf < 4; ++mf)
#pragma unroll
    for (int nf = 0; nf < 4; ++nf)
#pragma unroll
      for (int r = 0; r < 4; ++r)
        sC[(wm*64 + mf*16 + l4*4 + r)*136 + wn*64 + nf*16 + l15] = f2h_u(acc[mf][nf][r]);
  __syncthreads();
  // write 8 time-slabs: projT[row][col][b], 4 KB contiguous each
  int c = tid >> 1, half = tid & 1;      // c 0..127, half 0..1 (b 0..7 / 8..15)
#pragma unroll
  for (int ti = 0; ti < 8; ++ti){
    unsigned short* slab = Cd + ((size_t)(mt*8 + ti)*GG + nt*128)*16;
    unsigned short v[8];
#pragma unroll
    for (int j = 0; j < 8; ++j)
      v[j] = sC[((half*8 + j)*8 + ti)*136 + c];
    uint4 pk;
    pk.x = (unsigned int)v[0] | ((unsigned int)v[1] << 16);
    pk.y = (unsigned int)v[2] | ((unsigned int)v[3] << 16);
    pk.z = (unsigned int)v[4] | ((unsigned int)v[5] << 16);
    pk.w = (unsigned int)v[6] | ((unsigned int)v[7] << 16);
    *(uint4*)(slab + c*16 + half*8) = pk;
  }
}

// ---- MFMA LSTM scan: 2 blocks per direction, pairwise h-exchange ----------
template<int P>
__device__ __forceinline__ void scan_body(
    unsigned short (*h_lds)[264],
    const unsigned short* __restrict__ projT,  // [2][Tc][1024][16] f16
    const unsigned short* __restrict__ Rt,     // [2][1024][256] f16
    const float* __restrict__ bcf, const float* __restrict__ bcb,
    float* __restrict__ out,
    float* __restrict__ stH, float* __restrict__ stC,
    unsigned long long* __restrict__ xchg,     // [2 dir][2 slot][256 unit-grp... 1024 ull each]
    int* __restrict__ flags,                   // [4][32] int
    int t0, int t1, int Tc, int first, int d)
{
  int tid = threadIdx.x;
  int w = tid >> 6, l = tid & 63, l15 = l & 15, l4 = l >> 4;
  int u0 = P*128 + w*16;                 // wave's global unit base
  int b4 = l4*4;

  // ---- register-resident B-fragments of R: rf[gate][ks], 128 VGPRs, PINNED ----
  u32x4 rf[4][8];
  {
    const unsigned short* Rd = Rt + (size_t)d*1024*256;
#pragma unroll
    for (int g = 0; g < 4; ++g){
      const unsigned short* colp = Rd + (size_t)(g*256 + u0 + l15)*256 + l4*8;
#pragma unroll
      for (int ks = 0; ks < 8; ++ks)
        rf[g][ks] = *(const u32x4*)(colp + ks*32);
    }
  }
  // pin: asm-defined values cannot be rematerialized -> stay in VGPRs
#pragma unroll
  for (int g = 0; g < 4; ++g)
#pragma unroll
    for (int ks = 0; ks < 8; ++ks)
      asm volatile("" : "+v"(rf[g][ks]));

  // ---- init h_lds (full h: both halves) + c-state ----
  const float* stHb = stH + d*16*256;
  for (int idx = tid; idx < 16*264; idx += 512){
    int bb = idx / 264, cc = idx - bb*264;
    unsigned short v = 0;
    if (cc < 256 && !first) v = f2h_u(stHb[bb*256 + cc]);
    h_lds[bb][cc] = v;
  }
  f32x4 cst = {0.f,0.f,0.f,0.f};
  if (!first){
#pragma unroll
    for (int r = 0; r < 4; ++r)
      cst[r] = stC[((size_t)d*16 + b4 + r)*256 + u0 + l15];
  }
  float bc_r = (d ? bcb : bcf)[u0 + l15];

  const int me = d*2 + P, pa = d*2 + (1-P);
  constexpr int OWN_KS = P*4;            // own K-steps (own unit half feeds these k)
  constexpr int PAR_KS = 4 - P*4;
  constexpr int PAR_UB = (1-P)*128;

  // loop-invariant address pieces
  const unsigned short* prj = projT + (size_t)d*Tc*16384;
  int poff[4];
#pragma unroll
  for (int g = 0; g < 4; ++g) poff[g] = (g*256 + u0 + l15)*16 + b4;
  float* outb = out + (size_t)b4*TT*512 + d*256 + u0 + l15;
  size_t xw_base = ((size_t)d*2)*1024 + (u0 + l15)*4 + l4;          // + (s&1)*1024
  size_t xrd_dir = ((size_t)d*2)*1024;

  const int Tl = t1 - t0;
  float hh[4] = {0.f,0.f,0.f,0.f};

  __syncthreads();

  for (int s = 0; s < Tl; ++s){
    int t = t0 + s;
    int ps = d ? (Tl - 1 - s) : s;
    // issue proj loads first (consumed in epilogue; long slack)
    const unsigned short* pr = prj + (size_t)ps*16384;
    uint2 pj0 = *(const uint2*)(pr + poff[0]);
    uint2 pj1 = *(const uint2*)(pr + poff[1]);
    uint2 pj2 = *(const uint2*)(pr + poff[2]);
    uint2 pj3 = *(const uint2*)(pr + poff[3]);

    f32x4 acc0 = {0.f,0.f,0.f,0.f}, acc1 = acc0, acc2 = acc0, acc3 = acc0;
    // ---- phase A: own-half K (h written by this block last step) ----
#pragma unroll
    for (int ks = 0; ks < 4; ++ks){
      f16x8 af = *(const f16x8*)&h_lds[l15][(OWN_KS + ks)*32 + l4*8];
      acc0 = mfma16x16x32_f16(af, __builtin_bit_cast(f16x8, rf[0][OWN_KS + ks]), acc0);
      acc1 = mfma16x16x32_f16(af, __builtin_bit_cast(f16x8, rf[1][OWN_KS + ks]), acc1);
      acc2 = mfma16x16x32_f16(af, __builtin_bit_cast(f16x8, rf[2][OWN_KS + ks]), acc2);
      acc3 = mfma16x16x32_f16(af, __builtin_bit_cast(f16x8, rf[3][OWN_KS + ks]), acc3);
    }
    // ---- wave 0 only: poll partner flag (relaxed, no invalidates) + import ----
    if (s > 0 && w == 0){
      while (__hip_atomic_load(&flags[pa*32], __ATOMIC_RELAXED, __HIP_MEMORY_SCOPE_AGENT) < s)
        __builtin_amdgcn_s_sleep(1);
      size_t slot = (size_t)((s-1)&1)*1024 + xrd_dir;
#pragma unroll
      for (int q = 0; q < 8; ++q){
        int idx = q*64 + l;                        // 0..511
        int unit = PAR_UB + (idx >> 2);
        int grp  = idx & 3;
        unsigned long long v = __hip_atomic_load(&xchg[slot + unit*4 + grp],
                                                 __ATOMIC_RELAXED, __HIP_MEMORY_SCOPE_AGENT);
#pragma unroll
        for (int rr = 0; rr < 4; ++rr)
          h_lds[grp*4 + rr][unit] = (unsigned short)(v >> (16*rr));
      }
    }
    __syncthreads();
    // ---- phase B: partner-half K ----
#pragma unroll
    for (int ks = 0; ks < 4; ++ks){
      f16x8 af = *(const f16x8*)&h_lds[l15][(PAR_KS + ks)*32 + l4*8];
      acc0 = mfma16x16x32_f16(af, __builtin_bit_cast(f16x8, rf[0][PAR_KS + ks]), acc0);
      acc1 = mfma16x16x32_f16(af, __builtin_bit_cast(f16x8, rf[1][PAR_KS + ks]), acc1);
      acc2 = mfma16x16x32_f16(af, __builtin_bit_cast(f16x8, rf[2][PAR_KS + ks]), acc2);
      acc3 = mfma16x16x32_f16(af, __builtin_bit_cast(f16x8, rf[3][PAR_KS + ks]), acc3);
    }
    // ---- epilogue: gates + state update (4 batches per lane) ----
    float pjf0[4], pjf1[4], pjf2[4], pjf3[4];
    pjf0[0]=h2f((unsigned short)pj0.x); pjf0[1]=h2f((unsigned short)(pj0.x>>16));
    pjf0[2]=h2f((unsigned short)pj0.y); pjf0[3]=h2f((unsigned short)(pj0.y>>16));
    pjf1[0]=h2f((unsigned short)pj1.x); pjf1[1]=h2f((unsigned short)(pj1.x>>16));
    pjf1[2]=h2f((unsigned short)pj1.y); pjf1[3]=h2f((unsigned short)(pj1.y>>16));
    pjf2[0]=h2f((unsigned short)pj2.x); pjf2[1]=h2f((unsigned short)(pj2.x>>16));
    pjf2[2]=h2f((unsigned short)pj2.y); pjf2[3]=h2f((unsigned short)(pj2.y>>16));
    pjf3[0]=h2f((unsigned short)pj3.x); pjf3[1]=h2f((unsigned short)(pj3.x>>16));
    pjf3[2]=h2f((unsigned short)pj3.y); pjf3[3]=h2f((unsigned short)(pj3.y>>16));
    unsigned long long xv = 0;
#pragma unroll
    for (int r = 0; r < 4; ++r){
      float gi = acc0[r] + pjf0[r];
      float gf = acc1[r] + pjf1[r];
      float go = acc2[r] + pjf2[r];
      float gc = acc3[r] + pjf3[r] + bc_r;
      float ig = sigmoid_f(gi);
      float fg = sigmoid_f(gf);
      float og = sigmoid_f(go);
      float cand = tanh_f(gc);
      cst[r] = sigmoid_f(fg*cst[r] + ig*cand);     // faithful quirk
      float h = tanh_f(cst[r]) * og;               // faithful quirk
      outb[((size_t)r*TT + t)*512] = h;
      hh[r] = h;
      unsigned short hu = f2h_u(h);
      h_lds[b4 + r][u0 + l15] = hu;                // own half (disjoint from phase-B reads)
      xv |= (unsigned long long)hu << (16*r);
    }
    __hip_atomic_store(&xchg[xw_base + (size_t)(s&1)*1024], xv,
                       __ATOMIC_RELAXED, __HIP_MEMORY_SCOPE_AGENT);
    asm volatile("s_waitcnt vmcnt(0)" ::: "memory"); // belt: own stores at coherence point
    __syncthreads();                                 // all waves' stores drained + h_lds done
    if (tid == 0)
      __hip_atomic_store(&flags[me*32], s+1, __ATOMIC_RELAXED, __HIP_MEMORY_SCOPE_AGENT);
  }

  // chunk-carry state
#pragma unroll
  for (int r = 0; r < 4; ++r){
    stC[((size_t)d*16 + b4 + r)*256 + u0 + l15] = cst[r];
    stH[((size_t)d*16 + b4 + r)*256 + u0 + l15] = hh[r];
  }
}

__global__ __attribute__((amdgpu_flat_work_group_size(512, 512), amdgpu_waves_per_eu(2, 2)))
void lstm_scan_mfma(const unsigned short* __restrict__ projT,
                    const unsigned short* __restrict__ Rt,
                    const float* __restrict__ bcf, const float* __restrict__ bcb,
                    float* __restrict__ out,
                    float* __restrict__ stH, float* __restrict__ stC,
                    unsigned long long* __restrict__ xchg,
                    int* __restrict__ flags,
                    int t0, int t1, int Tc, int first)
{
  __shared__ __align__(16) unsigned short h_lds[16][264];
  int blk = blockIdx.x;
  int d = blk & 7, p = blk >> 3;
  if (d >= 2) return;
  if (p == 0) scan_body<0>(h_lds, projT, Rt, bcf, bcb, out, stH, stC, xchg, flags, t0, t1, Tc, first, d);
  else        scan_body<1>(h_lds, projT, Rt, bcf, bcb, out, stH, stC, xchg, flags, t0, t1, Tc, first, d);
}

// ---- launcher -------------------------------------------------------------
extern "C" void kernel_launch(void* const* d_in, const int* in_sizes, int n_in,
                              void* d_out, int out_size, void* d_ws, size_t ws_size,
                              hipStream_t stream){
  const float* x   = (const float*)d_in[0];
  const float* Wf  = (const float*)d_in[1];
  const float* Rf  = (const float*)d_in[2];
  const float* bcf = (const float*)d_in[3];
  const float* Wb  = (const float*)d_in[4];
  const float* Rb  = (const float*)d_in[5];
  const float* bcb = (const float*)d_in[6];
  float* out = (float*)d_out;
  char* ws = (char*)d_ws;

  const size_t OFF_XH    = 0;                        // 16 MiB: x bf16
  const size_t OFF_WT    = 16777216;                 // 1 MiB: W^T bf16 both dirs
  const size_t OFF_RT    = OFF_WT + 1048576;         // 1 MiB: R^T f16 both dirs
  const size_t OFF_STH   = OFF_RT + 1048576;         // 32 KiB h state
  const size_t OFF_STC   = OFF_STH + 32768;          // 32 KiB c state
  const size_t OFF_XCHG  = OFF_STC + 32768;          // 32 KiB h exchange
  const size_t OFF_FLAGS = OFF_XCHG + 32768;         // flags
  const size_t OFF_PROJT = OFF_FLAGS + 4096;         // projT chunk buffer

  unsigned short* xh    = (unsigned short*)(ws + OFF_XH);
  unsigned short* wt    = (unsigned short*)(ws + OFF_WT);
  unsigned short* rt    = (unsigned short*)(ws + OFF_RT);
  float*          stH   = (float*)(ws + OFF_STH);
  float*          stC   = (float*)(ws + OFF_STC);
  unsigned long long* xchg = (unsigned long long*)(ws + OFF_XCHG);
  int*            flags = (int*)(ws + OFF_FLAGS);
  unsigned short* projT = (unsigned short*)(ws + OFF_PROJT);

  int Tc = TT;  // time-chunk; shrink if ws too small (projT = 65536*Tc bytes)
  while (Tc > 128 && OFF_PROJT + (size_t)65536*Tc > ws_size) Tc >>= 1;

  cvt_x_kernel<<<8192, 256, 0, stream>>>(x, xh);
  cvt_wt_kernel<<<2048, 256, 0, stream>>>(Wf, Wb, wt);
  cvt_rt_kernel<<<512, 256, 0, stream>>>(Rf, Rb, rt);

  int nch = TT / Tc;
  for (int ch = 0; ch < nch; ++ch){
    int t0 = ch*Tc, t1 = t0 + Tc;
    gemm_projT<<<Tc, 256, 0, stream>>>(xh, wt,          projT,                     t0,      Tc);
    gemm_projT<<<Tc, 256, 0, stream>>>(xh, wt + 262144, projT + (size_t)Tc*GG*16,  TT - t1, Tc);
    hipMemsetAsync(flags, 0, 512, stream);
    lstm_scan_mfma<<<16, 512, 0, stream>>>(projT, rt, bcf, bcb, out, stH, stC, xchg, flags,
                                           t0, t1, Tc, ch == 0 ? 1 : 0);
  }
}

// Round 5
// 6448.204 us; speedup vs baseline: 1.4980x; 1.4980x over previous
//
#include <hip/hip_runtime.h>
#include <hip/hip_bf16.h>
#include <hip/hip_fp16.h>

#define TT 2048
#define BB 16
#define DD 256
#define GG 1024   // 4U
#define UU 256
#define NREGF 14  // fragments (of 32) per wave kept in registers; 18 in LDS

using f32x4  = __attribute__((ext_vector_type(4))) float;
using short8 = __attribute__((ext_vector_type(8))) short;
using f16x8  = __attribute__((ext_vector_type(8))) _Float16;
using u32x4  = __attribute__((ext_vector_type(4))) unsigned int;

static __device__ __forceinline__ unsigned short f2h_u(float f){
  _Float16 h = (_Float16)f;
  return __builtin_bit_cast(unsigned short, h);
}
static __device__ __forceinline__ float h2f(unsigned short u){
  return (float)__builtin_bit_cast(_Float16, u);
}
static __device__ __forceinline__ unsigned short f2bf_u(float f){
  __hip_bfloat16 b = __float2bfloat16(f);
  return __builtin_bit_cast(unsigned short, b);
}
static __device__ __forceinline__ float sigmoid_f(float x){
  return 1.0f / (1.0f + __expf(-x));
}
static __device__ __forceinline__ float tanh_f(float x){
  float ax = fabsf(x);
  float e  = __expf(2.0f*ax);          // overflow -> inf is fine: r -> 1
  float r  = 1.0f - 2.0f/(e + 1.0f);
  return copysignf(r, x);
}
static __device__ __forceinline__ f32x4 mfma16x16x32_f16(f16x8 a, f16x8 b, f32x4 c){
  return __builtin_amdgcn_mfma_f32_16x16x32_f16(a, b, c, 0, 0, 0);
}

// ---- converts -------------------------------------------------------------
__global__ __launch_bounds__(256) void cvt_x_kernel(const float* __restrict__ x,
                                                    unsigned short* __restrict__ xh){
  int gid = blockIdx.x*256 + threadIdx.x;
  const float4* xv = (const float4*)x;
  float4 v = xv[gid];
  unsigned int u0 = (unsigned int)f2bf_u(v.x) | ((unsigned int)f2bf_u(v.y) << 16);
  unsigned int u1 = (unsigned int)f2bf_u(v.z) | ((unsigned int)f2bf_u(v.w) << 16);
  ((uint2*)xh)[gid] = make_uint2(u0, u1);
}

// W [256][1024] f32 -> W^T bf16 [dir][1024][256]
__global__ __launch_bounds__(256) void cvt_wt_kernel(const float* __restrict__ Wf,
                                                     const float* __restrict__ Wb,
                                                     unsigned short* __restrict__ wt){
  int gid = blockIdx.x*256 + threadIdx.x;
  int d   = gid >> 18;
  int rem = gid & 262143;
  int n   = rem >> 8;
  int k   = rem & 255;
  const float* src = d ? Wb : Wf;
  wt[gid] = f2bf_u(src[k*GG + n]);
}

// R [256][1024] f32 -> R^T f16 [dir][1024 col][256 k]
__global__ __launch_bounds__(256) void cvt_rt_kernel(const float* __restrict__ Rf,
                                                     const float* __restrict__ Rb,
                                                     unsigned short* __restrict__ rt){
  int gid = blockIdx.x*256 + threadIdx.x;
  int d   = gid >> 16;
  int rem = gid & 65535;
  int col = rem >> 6;
  int k4  = (rem & 63) << 2;
  const float* src = d ? Rb : Rf;
  unsigned int u0 = (unsigned int)f2h_u(src[(k4+0)*GG + col]) |
                    ((unsigned int)f2h_u(src[(k4+1)*GG + col]) << 16);
  unsigned int u1 = (unsigned int)f2h_u(src[(k4+2)*GG + col]) |
                    ((unsigned int)f2h_u(src[(k4+3)*GG + col]) << 16);
  *(uint2*)(rt + ((size_t)d*1024 + col)*256 + k4) = make_uint2(u0, u1);
}

// ---- proj GEMM: M-tile = 16 batches x 8 timesteps; writes projT[t][col][16b]
__global__ __launch_bounds__(256) void gemm_projT(const unsigned short* __restrict__ Ah,
                                                  const unsigned short* __restrict__ BTh,
                                                  unsigned short* __restrict__ Cd,
                                                  int xstart, int Tc){
  __shared__ __align__(16) unsigned short smem[18432];
  unsigned short* sA = smem;             // [128][72]
  unsigned short* sB = smem + 9216;      // [128][72]
  unsigned short* sC = smem;             // [128][136]

  int mt  = blockIdx.x >> 3;
  int nt  = blockIdx.x & 7;
  int tid = threadIdx.x;

  const unsigned short* Bb = BTh + (size_t)nt*128*DD;

  int w = tid >> 6, lane = tid & 63, l15 = lane & 15, l4 = lane >> 4;
  int wm = w >> 1, wn = w & 1;

  f32x4 zero4 = {0.0f, 0.0f, 0.0f, 0.0f};
  f32x4 acc[4][4];
#pragma unroll
  for (int i = 0; i < 4; ++i)
#pragma unroll
    for (int j = 0; j < 4; ++j) acc[i][j] = zero4;

  for (int kt = 0; kt < 4; ++kt){
    __syncthreads();
#pragma unroll
    for (int i = 0; i < 4; ++i){
      int ch = tid + i*256;
      int r = ch >> 3, c8 = ch & 7;
      int bb = r >> 3, ti = r & 7;
      int tx = xstart + mt*8 + ti;
      *(uint4*)(sA + r*72 + c8*8) = *(const uint4*)(Ah + ((size_t)bb*TT + tx)*DD + kt*64 + c8*8);
      *(uint4*)(sB + r*72 + c8*8) = *(const uint4*)(Bb + (size_t)r*DD + kt*64 + c8*8);
    }
    __syncthreads();
#pragma unroll
    for (int ks = 0; ks < 2; ++ks){
      short8 a[4], b[4];
#pragma unroll
      for (int mf = 0; mf < 4; ++mf)
        a[mf] = *(const short8*)(sA + (wm*64 + mf*16 + l15)*72 + ks*32 + l4*8);
#pragma unroll
      for (int nf = 0; nf < 4; ++nf)
        b[nf] = *(const short8*)(sB + (wn*64 + nf*16 + l15)*72 + ks*32 + l4*8);
#pragma unroll
      for (int mf = 0; mf < 4; ++mf)
#pragma unroll
        for (int nf = 0; nf < 4; ++nf)
          acc[mf][nf] = __builtin_amdgcn_mfma_f32_16x16x32_bf16(a[mf], b[nf], acc[mf][nf], 0, 0, 0);
    }
  }
  __syncthreads();
#pragma unroll
  for (int mf = 0; mf < 4; ++mf)
#pragma unroll
    for (int nf = 0; nf < 4; ++nf)
#pragma unroll
      for (int r = 0; r < 4; ++r)
        sC[(wm*64 + mf*16 + l4*4 + r)*136 + wn*64 + nf*16 + l15] = f2h_u(acc[mf][nf][r]);
  __syncthreads();
  int c = tid >> 1, half = tid & 1;
#pragma unroll
  for (int ti = 0; ti < 8; ++ti){
    unsigned short* slab = Cd + ((size_t)(mt*8 + ti)*GG + nt*128)*16;
    unsigned short v[8];
#pragma unroll
    for (int j = 0; j < 8; ++j)
      v[j] = sC[((half*8 + j)*8 + ti)*136 + c];
    uint4 pk;
    pk.x = (unsigned int)v[0] | ((unsigned int)v[1] << 16);
    pk.y = (unsigned int)v[2] | ((unsigned int)v[3] << 16);
    pk.z = (unsigned int)v[4] | ((unsigned int)v[5] << 16);
    pk.w = (unsigned int)v[6] | ((unsigned int)v[7] << 16);
    *(uint4*)(slab + c*16 + half*8) = pk;
  }
}

// ---- B-fragment getter: reg if fidx<NREGF else per-thread LDS slot --------
template<int G, int KS>
static __device__ __forceinline__ f16x8 get_bfrag(const u32x4* rf,
                                                  const unsigned short* fr_lds,
                                                  int wl /* w*64+l */){
  constexpr int fidx = KS*4 + G;
  if constexpr (fidx < NREGF){
    return __builtin_bit_cast(f16x8, rf[fidx]);
  } else {
    // layout: [w][fidx-NREGF][lane][8 f16] -> per-wave sequential, conflict-free
    int w = wl >> 6, l = wl & 63;
    return *(const f16x8*)&fr_lds[(((w*(32-NREGF)) + (fidx - NREGF))*64 + l)*8];
  }
}

// ---- MFMA LSTM scan: 2 blocks per direction, R CU-resident (LDS+regs) -----
template<int P>
__device__ __forceinline__ void scan_body(
    unsigned short (*h_lds)[264],
    unsigned short* fr_lds,
    const unsigned short* __restrict__ projT,  // [2][Tc][1024][16] f16
    const unsigned short* __restrict__ Rt,     // [2][1024][256] f16
    const float* __restrict__ bcf, const float* __restrict__ bcb,
    float* __restrict__ out,
    float* __restrict__ stH, float* __restrict__ stC,
    unsigned long long* __restrict__ xchg,     // [2 dir][2 slot][256 unit][4 bgrp]
    int* __restrict__ flags,                   // [4][32] int
    int t0, int t1, int Tc, int first, int d)
{
  int tid = threadIdx.x;
  int w = tid >> 6, l = tid & 63, l15 = l & 15, l4 = l >> 4;
  int u0 = P*128 + w*16;                 // wave's global unit base
  int b4 = l4*4;

  // ---- stage R fragments: 14 in regs (56 VGPR), 18 in per-thread LDS slots
  const unsigned short* Rd = Rt + (size_t)d*1024*256;
  u32x4 rf[NREGF];
#pragma unroll
  for (int fidx = 0; fidx < 32; ++fidx){
    int g = fidx & 3, ks = fidx >> 2;    // fidx = ks*4 + g
    const unsigned short* src = Rd + (size_t)(g*256 + u0 + l15)*256 + l4*8 + ks*32;
    if (fidx < NREGF)
      rf[fidx] = *(const u32x4*)src;
    else
      *(u32x4*)&fr_lds[(((w*(32-NREGF)) + (fidx - NREGF))*64 + l)*8] = *(const u32x4*)src;
  }
#pragma unroll
  for (int i = 0; i < NREGF; ++i)
    asm volatile("" : "+v"(rf[i]));      // block remat (pressure is low; no spill risk)

  // ---- init h_lds (both halves) + c-state ----
  const float* stHb = stH + d*16*256;
  for (int idx = tid; idx < 16*264; idx += 512){
    int bb = idx / 264, cc = idx - bb*264;
    unsigned short v = 0;
    if (cc < 256 && !first) v = f2h_u(stHb[bb*256 + cc]);
    h_lds[bb][cc] = v;
  }
  f32x4 cst = {0.f,0.f,0.f,0.f};
  if (!first){
#pragma unroll
    for (int r = 0; r < 4; ++r)
      cst[r] = stC[((size_t)d*16 + b4 + r)*256 + u0 + l15];
  }
  float bc_r = (d ? bcb : bcf)[u0 + l15];

  const int me = d*2 + P, pa = d*2 + (1-P);
  constexpr int OWN_KS = P*4;            // own unit half feeds k-slices [4P,4P+4)
  constexpr int PAR_KS = 4 - P*4;
  constexpr int PAR_UB = (1-P)*128;

  const unsigned short* prj = projT + (size_t)d*Tc*16384;
  int poff[4];
#pragma unroll
  for (int g = 0; g < 4; ++g) poff[g] = (g*256 + u0 + l15)*16 + b4;
  float* outb = out + (size_t)b4*TT*512 + d*256 + u0 + l15;
  size_t xw_base = ((size_t)d*2)*1024 + (u0 + l15)*4 + l4;
  size_t xi_base = ((size_t)d*2)*1024 + (PAR_UB + (tid >> 2))*4 + (tid & 3);
  int imp_row = (tid & 3)*4, imp_col = PAR_UB + (tid >> 2);

  const int Tl = t1 - t0;
  float hh[4] = {0.f,0.f,0.f,0.f};

  __syncthreads();

#define PHASE_STEP(KS) { \
    f16x8 af = *(const f16x8*)&h_lds[l15][(KS)*32 + l4*8]; \
    acc0 = mfma16x16x32_f16(af, get_bfrag<0,(KS)>(rf, fr_lds, tid), acc0); \
    acc1 = mfma16x16x32_f16(af, get_bfrag<1,(KS)>(rf, fr_lds, tid), acc1); \
    acc2 = mfma16x16x32_f16(af, get_bfrag<2,(KS)>(rf, fr_lds, tid), acc2); \
    acc3 = mfma16x16x32_f16(af, get_bfrag<3,(KS)>(rf, fr_lds, tid), acc3); }

  for (int s = 0; s < Tl; ++s){
    int t = t0 + s;
    int ps = d ? (Tl - 1 - s) : s;
    // proj loads: consumed only in epilogue -> latency hidden under both phases
    const unsigned short* pr = prj + (size_t)ps*16384;
    uint2 pj0 = *(const uint2*)(pr + poff[0]);
    uint2 pj1 = *(const uint2*)(pr + poff[1]);
    uint2 pj2 = *(const uint2*)(pr + poff[2]);
    uint2 pj3 = *(const uint2*)(pr + poff[3]);

    // ---- poll partner flag (set ~a full phase ago in steady state), then
    //      issue the 8B import load; it flies during phase A ----
    unsigned long long vimp = 0;
    if (s > 0){
      while (__hip_atomic_load(&flags[pa*32], __ATOMIC_RELAXED, __HIP_MEMORY_SCOPE_AGENT) < s)
        __builtin_amdgcn_s_sleep(1);
      vimp = __hip_atomic_load(&xchg[xi_base + (size_t)((s-1)&1)*1024],
                               __ATOMIC_RELAXED, __HIP_MEMORY_SCOPE_AGENT);
    }

    f32x4 acc0 = {0.f,0.f,0.f,0.f}, acc1 = acc0, acc2 = acc0, acc3 = acc0;
    // ---- phase A: own-half k-slices (own h written by this block last step)
    PHASE_STEP(OWN_KS + 0)
    PHASE_STEP(OWN_KS + 1)
    PHASE_STEP(OWN_KS + 2)
    PHASE_STEP(OWN_KS + 3)

    // ---- land the import into the partner half of h_lds ----
    if (s > 0){
#pragma unroll
      for (int rr = 0; rr < 4; ++rr)
        h_lds[imp_row + rr][imp_col] = (unsigned short)(vimp >> (16*rr));
    }
    __syncthreads();

    // ---- phase B: partner-half k-slices ----
    PHASE_STEP(PAR_KS + 0)
    PHASE_STEP(PAR_KS + 1)
    PHASE_STEP(PAR_KS + 2)
    PHASE_STEP(PAR_KS + 3)

    // ---- epilogue: gates + state update (4 batches per lane, 1 unit) ----
    float pjf0[4], pjf1[4], pjf2[4], pjf3[4];
    pjf0[0]=h2f((unsigned short)pj0.x); pjf0[1]=h2f((unsigned short)(pj0.x>>16));
    pjf0[2]=h2f((unsigned short)pj0.y); pjf0[3]=h2f((unsigned short)(pj0.y>>16));
    pjf1[0]=h2f((unsigned short)pj1.x); pjf1[1]=h2f((unsigned short)(pj1.x>>16));
    pjf1[2]=h2f((unsigned short)pj1.y); pjf1[3]=h2f((unsigned short)(pj1.y>>16));
    pjf2[0]=h2f((unsigned short)pj2.x); pjf2[1]=h2f((unsigned short)(pj2.x>>16));
    pjf2[2]=h2f((unsigned short)pj2.y); pjf2[3]=h2f((unsigned short)(pj2.y>>16));
    pjf3[0]=h2f((unsigned short)pj3.x); pjf3[1]=h2f((unsigned short)(pj3.x>>16));
    pjf3[2]=h2f((unsigned short)pj3.y); pjf3[3]=h2f((unsigned short)(pj3.y>>16));
    unsigned long long xv = 0;
#pragma unroll
    for (int r = 0; r < 4; ++r){
      float gi = acc0[r] + pjf0[r];
      float gf = acc1[r] + pjf1[r];
      float go = acc2[r] + pjf2[r];
      float gc = acc3[r] + pjf3[r] + bc_r;
      float ig = sigmoid_f(gi);
      float fg = sigmoid_f(gf);
      float og = sigmoid_f(go);
      float cand = tanh_f(gc);
      cst[r] = sigmoid_f(fg*cst[r] + ig*cand);     // faithful quirk
      float h = tanh_f(cst[r]) * og;               // faithful quirk
      outb[((size_t)r*TT + t)*512] = h;
      hh[r] = h;
      unsigned short hu = f2h_u(h);
      h_lds[b4 + r][u0 + l15] = hu;                // own half
      xv |= (unsigned long long)hu << (16*r);
    }
    __hip_atomic_store(&xchg[xw_base + (size_t)(s&1)*1024], xv,
                       __ATOMIC_RELAXED, __HIP_MEMORY_SCOPE_AGENT);
    asm volatile("s_waitcnt vmcnt(0)" ::: "memory"); // export at coherence point
    __syncthreads();                                 // + all h_lds writes visible
    if (tid == 0)
      __hip_atomic_store(&flags[me*32], s+1, __ATOMIC_RELAXED, __HIP_MEMORY_SCOPE_AGENT);
  }
#undef PHASE_STEP

  // chunk-carry state
#pragma unroll
  for (int r = 0; r < 4; ++r){
    stC[((size_t)d*16 + b4 + r)*256 + u0 + l15] = cst[r];
    stH[((size_t)d*16 + b4 + r)*256 + u0 + l15] = hh[r];
  }
}

__global__ __launch_bounds__(512, 1)
void lstm_scan_mfma(const unsigned short* __restrict__ projT,
                    const unsigned short* __restrict__ Rt,
                    const float* __restrict__ bcf, const float* __restrict__ bcb,
                    float* __restrict__ out,
                    float* __restrict__ stH, float* __restrict__ stC,
                    unsigned long long* __restrict__ xchg,
                    int* __restrict__ flags,
                    int t0, int t1, int Tc, int first)
{
  __shared__ __align__(16) unsigned short h_lds[16][264];            // 8448 B
  __shared__ __align__(16) unsigned short fr_lds[8*(32-NREGF)*64*8]; // 147456 B
  int blk = blockIdx.x;
  int d = blk & 7, p = blk >> 3;
  if (d >= 2) return;
  if (p == 0) scan_body<0>(h_lds, fr_lds, projT, Rt, bcf, bcb, out, stH, stC, xchg, flags, t0, t1, Tc, first, d);
  else        scan_body<1>(h_lds, fr_lds, projT, Rt, bcf, bcb, out, stH, stC, xchg, flags, t0, t1, Tc, first, d);
}

// ---- launcher -------------------------------------------------------------
extern "C" void kernel_launch(void* const* d_in, const int* in_sizes, int n_in,
                              void* d_out, int out_size, void* d_ws, size_t ws_size,
                              hipStream_t stream){
  const float* x   = (const float*)d_in[0];
  const float* Wf  = (const float*)d_in[1];
  const float* Rf  = (const float*)d_in[2];
  const float* bcf = (const float*)d_in[3];
  const float* Wb  = (const float*)d_in[4];
  const float* Rb  = (const float*)d_in[5];
  const float* bcb = (const float*)d_in[6];
  float* out = (float*)d_out;
  char* ws = (char*)d_ws;

  const size_t OFF_XH    = 0;                        // 16 MiB: x bf16
  const size_t OFF_WT    = 16777216;                 // 1 MiB: W^T bf16 both dirs
  const size_t OFF_RT    = OFF_WT + 1048576;         // 1 MiB: R^T f16 both dirs
  const size_t OFF_STH   = OFF_RT + 1048576;         // 32 KiB h state
  const size_t OFF_STC   = OFF_STH + 32768;          // 32 KiB c state
  const size_t OFF_XCHG  = OFF_STC + 32768;          // 32 KiB h exchange
  const size_t OFF_FLAGS = OFF_XCHG + 32768;         // flags
  const size_t OFF_PROJT = OFF_FLAGS + 4096;         // projT chunk buffer

  unsigned short* xh    = (unsigned short*)(ws + OFF_XH);
  unsigned short* wt    = (unsigned short*)(ws + OFF_WT);
  unsigned short* rt    = (unsigned short*)(ws + OFF_RT);
  float*          stH   = (float*)(ws + OFF_STH);
  float*          stC   = (float*)(ws + OFF_STC);
  unsigned long long* xchg = (unsigned long long*)(ws + OFF_XCHG);
  int*            flags = (int*)(ws + OFF_FLAGS);
  unsigned short* projT = (unsigned short*)(ws + OFF_PROJT);

  int Tc = TT;  // time-chunk; shrink if ws too small (projT = 65536*Tc bytes)
  while (Tc > 128 && OFF_PROJT + (size_t)65536*Tc > ws_size) Tc >>= 1;

  cvt_x_kernel<<<8192, 256, 0, stream>>>(x, xh);
  cvt_wt_kernel<<<2048, 256, 0, stream>>>(Wf, Wb, wt);
  cvt_rt_kernel<<<512, 256, 0, stream>>>(Rf, Rb, rt);

  int nch = TT / Tc;
  for (int ch = 0; ch < nch; ++ch){
    int t0 = ch*Tc, t1 = t0 + Tc;
    gemm_projT<<<Tc, 256, 0, stream>>>(xh, wt,          projT,                     t0,      Tc);
    gemm_projT<<<Tc, 256, 0, stream>>>(xh, wt + 262144, projT + (size_t)Tc*GG*16,  TT - t1, Tc);
    hipMemsetAsync(flags, 0, 512, stream);
    lstm_scan_mfma<<<16, 512, 0, stream>>>(projT, rt, bcf, bcb, out, stH, stC, xchg, flags,
                                           t0, t1, Tc, ch == 0 ? 1 : 0);
  }
}

// Round 6
// 5217.273 us; speedup vs baseline: 1.8514x; 1.2359x over previous
//
#include <hip/hip_runtime.h>
#include <hip/hip_bf16.h>
#include <hip/hip_fp16.h>

#define TT 2048
#define BB 16
#define DD 256
#define GG 1024   // 4U
#define UU 256

using f32x4  = __attribute__((ext_vector_type(4))) float;
using short8 = __attribute__((ext_vector_type(8))) short;
using f16x8  = __attribute__((ext_vector_type(8))) _Float16;
using u32x4  = __attribute__((ext_vector_type(4))) unsigned int;

static __device__ __forceinline__ unsigned short f2h_u(float f){
  _Float16 h = (_Float16)f;
  return __builtin_bit_cast(unsigned short, h);
}
static __device__ __forceinline__ float h2f(unsigned short u){
  return (float)__builtin_bit_cast(_Float16, u);
}
static __device__ __forceinline__ unsigned short f2bf_u(float f){
  __hip_bfloat16 b = __float2bfloat16(f);
  return __builtin_bit_cast(unsigned short, b);
}
static __device__ __forceinline__ float sigmoid_f(float x){
  return 1.0f / (1.0f + __expf(-x));
}
static __device__ __forceinline__ float tanh_f(float x){
  float ax = fabsf(x);
  float e  = __expf(2.0f*ax);          // overflow -> inf is fine: r -> 1
  float r  = 1.0f - 2.0f/(e + 1.0f);
  return copysignf(r, x);
}
static __device__ __forceinline__ f32x4 mfma16x16x32_f16(f16x8 a, f16x8 b, f32x4 c){
  return __builtin_amdgcn_mfma_f32_16x16x32_f16(a, b, c, 0, 0, 0);
}

// ---- converts -------------------------------------------------------------
__global__ __launch_bounds__(256) void cvt_x_kernel(const float* __restrict__ x,
                                                    unsigned short* __restrict__ xh){
  int gid = blockIdx.x*256 + threadIdx.x;
  const float4* xv = (const float4*)x;
  float4 v = xv[gid];
  unsigned int u0 = (unsigned int)f2bf_u(v.x) | ((unsigned int)f2bf_u(v.y) << 16);
  unsigned int u1 = (unsigned int)f2bf_u(v.z) | ((unsigned int)f2bf_u(v.w) << 16);
  ((uint2*)xh)[gid] = make_uint2(u0, u1);
}

// W [256][1024] f32 -> W^T bf16 [dir][1024][256]
__global__ __launch_bounds__(256) void cvt_wt_kernel(const float* __restrict__ Wf,
                                                     const float* __restrict__ Wb,
                                                     unsigned short* __restrict__ wt){
  int gid = blockIdx.x*256 + threadIdx.x;
  int d   = gid >> 18;
  int rem = gid & 262143;
  int n   = rem >> 8;
  int k   = rem & 255;
  const float* src = d ? Wb : Wf;
  wt[gid] = f2bf_u(src[k*GG + n]);
}

// R [256][1024] f32 -> R^T f16 [dir][1024 col][256 k]
__global__ __launch_bounds__(256) void cvt_rt_kernel(const float* __restrict__ Rf,
                                                     const float* __restrict__ Rb,
                                                     unsigned short* __restrict__ rt){
  int gid = blockIdx.x*256 + threadIdx.x;
  int d   = gid >> 16;
  int rem = gid & 65535;
  int col = rem >> 6;
  int k4  = (rem & 63) << 2;
  const float* src = d ? Rb : Rf;
  unsigned int u0 = (unsigned int)f2h_u(src[(k4+0)*GG + col]) |
                    ((unsigned int)f2h_u(src[(k4+1)*GG + col]) << 16);
  unsigned int u1 = (unsigned int)f2h_u(src[(k4+2)*GG + col]) |
                    ((unsigned int)f2h_u(src[(k4+3)*GG + col]) << 16);
  *(uint2*)(rt + ((size_t)d*1024 + col)*256 + k4) = make_uint2(u0, u1);
}

// ---- proj GEMM: M-tile = 16 batches x 8 timesteps; writes projT[t][col][16b]
__global__ __launch_bounds__(256) void gemm_projT(const unsigned short* __restrict__ Ah,
                                                  const unsigned short* __restrict__ BTh,
                                                  unsigned short* __restrict__ Cd,
                                                  int xstart, int Tc){
  __shared__ __align__(16) unsigned short smem[18432];
  unsigned short* sA = smem;             // [128][72]
  unsigned short* sB = smem + 9216;      // [128][72]
  unsigned short* sC = smem;             // [128][136]

  int mt  = blockIdx.x >> 3;
  int nt  = blockIdx.x & 7;
  int tid = threadIdx.x;

  const unsigned short* Bb = BTh + (size_t)nt*128*DD;

  int w = tid >> 6, lane = tid & 63, l15 = lane & 15, l4 = lane >> 4;
  int wm = w >> 1, wn = w & 1;

  f32x4 zero4 = {0.0f, 0.0f, 0.0f, 0.0f};
  f32x4 acc[4][4];
#pragma unroll
  for (int i = 0; i < 4; ++i)
#pragma unroll
    for (int j = 0; j < 4; ++j) acc[i][j] = zero4;

  for (int kt = 0; kt < 4; ++kt){
    __syncthreads();
#pragma unroll
    for (int i = 0; i < 4; ++i){
      int ch = tid + i*256;
      int r = ch >> 3, c8 = ch & 7;
      int bb = r >> 3, ti = r & 7;
      int tx = xstart + mt*8 + ti;
      *(uint4*)(sA + r*72 + c8*8) = *(const uint4*)(Ah + ((size_t)bb*TT + tx)*DD + kt*64 + c8*8);
      *(uint4*)(sB + r*72 + c8*8) = *(const uint4*)(Bb + (size_t)r*DD + kt*64 + c8*8);
    }
    __syncthreads();
#pragma unroll
    for (int ks = 0; ks < 2; ++ks){
      short8 a[4], b[4];
#pragma unroll
      for (int mf = 0; mf < 4; ++mf)
        a[mf] = *(const short8*)(sA + (wm*64 + mf*16 + l15)*72 + ks*32 + l4*8);
#pragma unroll
      for (int nf = 0; nf < 4; ++nf)
        b[nf] = *(const short8*)(sB + (wn*64 + nf*16 + l15)*72 + ks*32 + l4*8);
#pragma unroll
      for (int mf = 0; mf < 4; ++mf)
#pragma unroll
        for (int nf = 0; nf < 4; ++nf)
          acc[mf][nf] = __builtin_amdgcn_mfma_f32_16x16x32_bf16(a[mf], b[nf], acc[mf][nf], 0, 0, 0);
    }
  }
  __syncthreads();
#pragma unroll
  for (int mf = 0; mf < 4; ++mf)
#pragma unroll
    for (int nf = 0; nf < 4; ++nf)
#pragma unroll
      for (int r = 0; r < 4; ++r)
        sC[(wm*64 + mf*16 + l4*4 + r)*136 + wn*64 + nf*16 + l15] = f2h_u(acc[mf][nf][r]);
  __syncthreads();
  int c = tid >> 1, half = tid & 1;
#pragma unroll
  for (int ti = 0; ti < 8; ++ti){
    unsigned short* slab = Cd + ((size_t)(mt*8 + ti)*GG + nt*128)*16;
    unsigned short v[8];
#pragma unroll
    for (int j = 0; j < 8; ++j)
      v[j] = sC[((half*8 + j)*8 + ti)*136 + c];
    uint4 pk;
    pk.x = (unsigned int)v[0] | ((unsigned int)v[1] << 16);
    pk.y = (unsigned int)v[2] | ((unsigned int)v[3] << 16);
    pk.z = (unsigned int)v[4] | ((unsigned int)v[5] << 16);
    pk.w = (unsigned int)v[6] | ((unsigned int)v[7] << 16);
    *(uint4*)(slab + c*16 + half*8) = pk;
  }
}

// ---- MFMA LSTM scan: 4 blocks per direction, all-to-all h exchange --------
// Block (d, Q) owns units [Q*64, Q*64+64). Wave w: gate-pair gp=w>>2 covers
// gates {2gp, 2gp+1}, N-tile nt=w&3 covers units Q*64+nt*16+[0,16).
// B-fragments: 16 per wave, register-resident (64 VGPR).
template<int Q>
__device__ __forceinline__ void scan_body(
    unsigned short (*h_lds)[264],              // [batch][global unit]
    f32x4 (*xg)[16][4],                        // gate exchange [wave][l15][l4]
    const unsigned short* __restrict__ projT,  // [2][Tc][1024][16] f16
    const unsigned short* __restrict__ Rt,     // [2][1024][256] f16
    const float* __restrict__ bcf, const float* __restrict__ bcb,
    float* __restrict__ out,
    float* __restrict__ stH, float* __restrict__ stC,
    unsigned int* __restrict__ xchg,           // [2 d][2 slot][8 bp][256 u] uint
    int* __restrict__ flags,                   // [8][32] int
    int t0, int t1, int Tc, int first, int d)
{
  int tid = threadIdx.x;
  int w = tid >> 6, l = tid & 63, l15 = l & 15, l4 = l >> 4;
  int gp = w >> 2, nt = w & 3;
  int ug = Q*64 + nt*16 + l15;           // global unit this lane owns
  int bb = l4*4 + gp*2;                  // first of the 2 batches this lane owns

  // ---- stage B-fragments: frag[0..7]=gate 2gp, frag[8..15]=gate 2gp+1 ----
  u32x4 frag[16];
  const unsigned short* Rd = Rt + (size_t)d*262144;
#pragma unroll
  for (int p01 = 0; p01 < 2; ++p01){
    const unsigned short* colp = Rd + (size_t)((gp*2 + p01)*256 + ug)*256 + l4*8;
#pragma unroll
    for (int ks = 0; ks < 8; ++ks)
      frag[p01*8 + ks] = *(const u32x4*)(colp + ks*32);
  }
#pragma unroll
  for (int i = 0; i < 16; ++i)
    asm volatile("" : "+v"(frag[i]));    // block remat; 64 VGPR is safely allocatable

  // ---- init h_lds (all 256 units) + c-state ----
  const float* stHb = stH + d*4096;
  for (int idx = tid; idx < 4096; idx += 512){
    int bbx = idx >> 8, cc = idx & 255;
    h_lds[bbx][cc] = first ? (unsigned short)0 : f2h_u(stHb[idx]);
  }
  float c0 = 0.f, c1 = 0.f, h0s = 0.f, h1s = 0.f;
  if (!first){
    c0 = stC[(d*16 + bb    )*256 + ug];
    c1 = stC[(d*16 + bb + 1)*256 + ug];
  }
  float bc_r = (d ? bcb : bcf)[ug];

  const unsigned short* prj = projT + (size_t)d*Tc*16384;
  const int po0 = (0*256 + ug)*16 + bb;
  const int po1 = (1*256 + ug)*16 + bb;
  const int po2 = (2*256 + ug)*16 + bb;
  const int po3 = (3*256 + ug)*16 + bb;
  const int myflag = (d*4 + Q)*32;
  const int pq = (Q + 1 + w) & 3;                 // partner (import waves 0..2)
  const int paflag = (d*4 + pq)*32;
  const size_t xex = ((size_t)(d*2)*8 + (bb >> 1))*256 + ug;   // + slot*2048
  unsigned long long* xb = (unsigned long long*)xchg;          // [d][slot][bp][128 upair]
  const size_t xib = (size_t)d*2048;                           // ull idx of [d][0][0][0]
  float* outb = out + d*256 + ug;
  const int Tl = t1 - t0;

  __syncthreads();

#define STEP_KS(ks_) { \
    f16x8 af = *(const f16x8*)&h_lds[l15][(ks_)*32 + l4*8]; \
    acc0 = mfma16x16x32_f16(af, __builtin_bit_cast(f16x8, frag[(ks_)]), acc0); \
    acc1 = mfma16x16x32_f16(af, __builtin_bit_cast(f16x8, frag[8 + (ks_)]), acc1); }

#define LAND(v_, e_) { int bp_ = (e_) >> 5; int uu_ = pq*64 + ((e_) & 31)*2; \
    *(unsigned int*)&h_lds[2*bp_    ][uu_] = (unsigned int)((v_) & 0xffffu) | ((unsigned int)(((v_) >> 32) & 0xffffu) << 16); \
    *(unsigned int*)&h_lds[2*bp_ + 1][uu_] = (unsigned int)(((v_) >> 16) & 0xffffu) | ((unsigned int)(((v_) >> 48) & 0xffffu) << 16); }

  for (int s = 0; s < Tl; ++s){
    int t = t0 + s;
    int ps = d ? (Tl - 1 - s) : s;
    const unsigned short* pr = prj + (size_t)ps*16384;
    unsigned int pj0 = *(const unsigned int*)(pr + po0);
    unsigned int pj1 = *(const unsigned int*)(pr + po1);
    unsigned int pj2 = *(const unsigned int*)(pr + po2);
    unsigned int pj3 = *(const unsigned int*)(pr + po3);

    // ---- waves 0..2: poll partner flag, issue 2KB slab import (4x 8B) ----
    unsigned long long iv0 = 0, iv1 = 0, iv2 = 0, iv3 = 0;
    if (s > 0 && w < 3){
      while (__hip_atomic_load(&flags[paflag], __ATOMIC_RELAXED, __HIP_MEMORY_SCOPE_AGENT) < s)
        __builtin_amdgcn_s_sleep(1);
      size_t base = xib + (size_t)((s - 1) & 1)*1024 + pq*32;
      iv0 = __hip_atomic_load(&xb[base + ((l      ) >> 5)*128 + ((l      ) & 31)], __ATOMIC_RELAXED, __HIP_MEMORY_SCOPE_AGENT);
      iv1 = __hip_atomic_load(&xb[base + ((l +  64) >> 5)*128 + ((l +  64) & 31)], __ATOMIC_RELAXED, __HIP_MEMORY_SCOPE_AGENT);
      iv2 = __hip_atomic_load(&xb[base + ((l + 128) >> 5)*128 + ((l + 128) & 31)], __ATOMIC_RELAXED, __HIP_MEMORY_SCOPE_AGENT);
      iv3 = __hip_atomic_load(&xb[base + ((l + 192) >> 5)*128 + ((l + 192) & 31)], __ATOMIC_RELAXED, __HIP_MEMORY_SCOPE_AGENT);
    }

    // ---- phase A: own 2 k-slices (k in [64Q, 64Q+64), local h) ----
    f32x4 acc0 = {0.f,0.f,0.f,0.f}, acc1 = acc0;
    STEP_KS(2*Q)
    STEP_KS(2*Q + 1)

    // ---- land imports into partner unit columns ----
    if (s > 0 && w < 3){
      LAND(iv0, l)
      LAND(iv1, l + 64)
      LAND(iv2, l + 128)
      LAND(iv3, l + 192)
    }
    __syncthreads();                      // B1: imports visible

    // ---- phase B: remaining 6 k-slices ----
#pragma unroll
    for (int ks = 0; ks < 8; ++ks)
      if (ks != 2*Q && ks != 2*Q + 1)
        STEP_KS(ks)

    // ---- gate exchange with buddy wave (w^4): give away other-batch pair --
    f32x4 give;
    if (gp == 0){ give[0] = acc0[2]; give[1] = acc1[2]; give[2] = acc0[3]; give[3] = acc1[3]; }
    else        { give[0] = acc0[0]; give[1] = acc1[0]; give[2] = acc0[1]; give[3] = acc1[1]; }
    xg[w][l15][l4] = give;
    __syncthreads();                      // B2: exchange visible
    f32x4 peer = xg[w ^ 4][l15][l4];

    float gi0, gf0, go0, gc0, gi1, gf1, go1, gc1;
    if (gp == 0){
      gi0 = acc0[0]; gf0 = acc1[0]; go0 = peer[0]; gc0 = peer[1];
      gi1 = acc0[1]; gf1 = acc1[1]; go1 = peer[2]; gc1 = peer[3];
    } else {
      gi0 = peer[0]; gf0 = peer[1]; go0 = acc0[2]; gc0 = acc1[2];
      gi1 = peer[2]; gf1 = peer[3]; go1 = acc0[3]; gc1 = acc1[3];
    }
    gi0 += h2f((unsigned short)pj0); gi1 += h2f((unsigned short)(pj0 >> 16));
    gf0 += h2f((unsigned short)pj1); gf1 += h2f((unsigned short)(pj1 >> 16));
    go0 += h2f((unsigned short)pj2); go1 += h2f((unsigned short)(pj2 >> 16));
    gc0 += h2f((unsigned short)pj3) + bc_r; gc1 += h2f((unsigned short)(pj3 >> 16)) + bc_r;

    float ig0 = sigmoid_f(gi0), fg0 = sigmoid_f(gf0), og0 = sigmoid_f(go0);
    float ig1 = sigmoid_f(gi1), fg1 = sigmoid_f(gf1), og1 = sigmoid_f(go1);
    float cd0 = tanh_f(gc0), cd1 = tanh_f(gc1);
    c0 = sigmoid_f(fg0*c0 + ig0*cd0);     // faithful quirk
    c1 = sigmoid_f(fg1*c1 + ig1*cd1);
    float h0 = tanh_f(c0) * og0;          // faithful quirk
    float h1 = tanh_f(c1) * og1;
    h0s = h0; h1s = h1;

    unsigned short hu0 = f2h_u(h0), hu1 = f2h_u(h1);
    h_lds[bb    ][ug] = hu0;              // own region, read by next phase A
    h_lds[bb + 1][ug] = hu1;
    __hip_atomic_store(&xchg[xex + (size_t)(s & 1)*2048],
                       (unsigned int)hu0 | ((unsigned int)hu1 << 16),
                       __ATOMIC_RELAXED, __HIP_MEMORY_SCOPE_AGENT);
    outb[((size_t)bb*TT + t)*512]       = h0;
    outb[((size_t)(bb + 1)*TT + t)*512] = h1;
    __syncthreads();                      // B3: drains vmcnt(0) -> exports at L2
    if (tid == 0)
      __hip_atomic_store(&flags[myflag], s + 1, __ATOMIC_RELAXED, __HIP_MEMORY_SCOPE_AGENT);
  }
#undef STEP_KS
#undef LAND

  // chunk-carry state
  stC[(d*16 + bb    )*256 + ug] = c0;
  stC[(d*16 + bb + 1)*256 + ug] = c1;
  stH[(d*16 + bb    )*256 + ug] = h0s;
  stH[(d*16 + bb + 1)*256 + ug] = h1s;
}

__global__ __launch_bounds__(512, 1)
void lstm_scan_mfma(const unsigned short* __restrict__ projT,
                    const unsigned short* __restrict__ Rt,
                    const float* __restrict__ bcf, const float* __restrict__ bcb,
                    float* __restrict__ out,
                    float* __restrict__ stH, float* __restrict__ stC,
                    unsigned int* __restrict__ xchg,
                    int* __restrict__ flags,
                    int t0, int t1, int Tc, int first)
{
  __shared__ __align__(16) unsigned short h_lds[16][264];  // 8448 B
  __shared__ __align__(16) f32x4 xg[8][16][4];             // 8192 B
  int blk = blockIdx.x;
  int d = blk & 7, q = blk >> 3;                           // blocks {d,d+8,d+16,d+24} -> XCD d
  if (d >= 2) return;
  switch (q){
    case 0: scan_body<0>(h_lds, xg, projT, Rt, bcf, bcb, out, stH, stC, xchg, flags, t0, t1, Tc, first, d); break;
    case 1: scan_body<1>(h_lds, xg, projT, Rt, bcf, bcb, out, stH, stC, xchg, flags, t0, t1, Tc, first, d); break;
    case 2: scan_body<2>(h_lds, xg, projT, Rt, bcf, bcb, out, stH, stC, xchg, flags, t0, t1, Tc, first, d); break;
    default: scan_body<3>(h_lds, xg, projT, Rt, bcf, bcb, out, stH, stC, xchg, flags, t0, t1, Tc, first, d); break;
  }
}

// ---- launcher -------------------------------------------------------------
extern "C" void kernel_launch(void* const* d_in, const int* in_sizes, int n_in,
                              void* d_out, int out_size, void* d_ws, size_t ws_size,
                              hipStream_t stream){
  const float* x   = (const float*)d_in[0];
  const float* Wf  = (const float*)d_in[1];
  const float* Rf  = (const float*)d_in[2];
  const float* bcf = (const float*)d_in[3];
  const float* Wb  = (const float*)d_in[4];
  const float* Rb  = (const float*)d_in[5];
  const float* bcb = (const float*)d_in[6];
  float* out = (float*)d_out;
  char* ws = (char*)d_ws;

  const size_t OFF_XH    = 0;                        // 16 MiB: x bf16
  const size_t OFF_WT    = 16777216;                 // 1 MiB: W^T bf16 both dirs
  const size_t OFF_RT    = OFF_WT + 1048576;         // 1 MiB: R^T f16 both dirs
  const size_t OFF_STH   = OFF_RT + 1048576;         // 32 KiB h state
  const size_t OFF_STC   = OFF_STH + 32768;          // 32 KiB c state
  const size_t OFF_XCHG  = OFF_STC + 32768;          // 64 KiB h exchange
  const size_t OFF_FLAGS = OFF_XCHG + 65536;         // 4 KiB flags
  const size_t OFF_PROJT = OFF_FLAGS + 4096;         // projT chunk buffer

  unsigned short* xh    = (unsigned short*)(ws + OFF_XH);
  unsigned short* wt    = (unsigned short*)(ws + OFF_WT);
  unsigned short* rt    = (unsigned short*)(ws + OFF_RT);
  float*          stH   = (float*)(ws + OFF_STH);
  float*          stC   = (float*)(ws + OFF_STC);
  unsigned int*   xchg  = (unsigned int*)(ws + OFF_XCHG);
  int*            flags = (int*)(ws + OFF_FLAGS);
  unsigned short* projT = (unsigned short*)(ws + OFF_PROJT);

  int Tc = TT;  // time-chunk; shrink if ws too small (projT = 65536*Tc bytes)
  while (Tc > 128 && OFF_PROJT + (size_t)65536*Tc > ws_size) Tc >>= 1;

  cvt_x_kernel<<<8192, 256, 0, stream>>>(x, xh);
  cvt_wt_kernel<<<2048, 256, 0, stream>>>(Wf, Wb, wt);
  cvt_rt_kernel<<<512, 256, 0, stream>>>(Rf, Rb, rt);

  int nch = TT / Tc;
  for (int ch = 0; ch < nch; ++ch){
    int t0 = ch*Tc, t1 = t0 + Tc;
    gemm_projT<<<Tc, 256, 0, stream>>>(xh, wt,          projT,                     t0,      Tc);
    gemm_projT<<<Tc, 256, 0, stream>>>(xh, wt + 262144, projT + (size_t)Tc*GG*16,  TT - t1, Tc);
    hipMemsetAsync(flags, 0, 4096, stream);
    lstm_scan_mfma<<<32, 512, 0, stream>>>(projT, rt, bcf, bcb, out, stH, stC, xchg, flags,
                                           t0, t1, Tc, ch == 0 ? 1 : 0);
  }
}

// Round 7
// 4396.007 us; speedup vs baseline: 2.1973x; 1.1868x over previous
//
#include <hip/hip_runtime.h>
#include <hip/hip_bf16.h>
#include <hip/hip_fp16.h>

#define TT 2048
#define BB 16
#define DD 256
#define GG 1024   // 4U
#define UU 256
#define NBLK 8    // blocks per direction; each owns 32 units

using f32x4  = __attribute__((ext_vector_type(4))) float;
using short8 = __attribute__((ext_vector_type(8))) short;
using f16x8  = __attribute__((ext_vector_type(8))) _Float16;
using u32x4  = __attribute__((ext_vector_type(4))) unsigned int;

static __device__ __forceinline__ unsigned short f2h_u(float f){
  _Float16 h = (_Float16)f;
  return __builtin_bit_cast(unsigned short, h);
}
static __device__ __forceinline__ float h2f(unsigned short u){
  return (float)__builtin_bit_cast(_Float16, u);
}
static __device__ __forceinline__ unsigned short f2bf_u(float f){
  __hip_bfloat16 b = __float2bfloat16(f);
  return __builtin_bit_cast(unsigned short, b);
}
static __device__ __forceinline__ float sigmoid_f(float x){
  return 1.0f / (1.0f + __expf(-x));
}
static __device__ __forceinline__ float tanh_f(float x){
  float ax = fabsf(x);
  float e  = __expf(2.0f*ax);          // overflow -> inf is fine: r -> 1
  float r  = 1.0f - 2.0f/(e + 1.0f);
  return copysignf(r, x);
}
static __device__ __forceinline__ f32x4 mfma16x16x32_f16(f16x8 a, f16x8 b, f32x4 c){
  return __builtin_amdgcn_mfma_f32_16x16x32_f16(a, b, c, 0, 0, 0);
}

// ---- converts -------------------------------------------------------------
__global__ __launch_bounds__(256) void cvt_x_kernel(const float* __restrict__ x,
                                                    unsigned short* __restrict__ xh){
  int gid = blockIdx.x*256 + threadIdx.x;
  const float4* xv = (const float4*)x;
  float4 v = xv[gid];
  unsigned int u0 = (unsigned int)f2bf_u(v.x) | ((unsigned int)f2bf_u(v.y) << 16);
  unsigned int u1 = (unsigned int)f2bf_u(v.z) | ((unsigned int)f2bf_u(v.w) << 16);
  ((uint2*)xh)[gid] = make_uint2(u0, u1);
}

// W [256][1024] f32 -> W^T bf16 [dir][1024][256]
__global__ __launch_bounds__(256) void cvt_wt_kernel(const float* __restrict__ Wf,
                                                     const float* __restrict__ Wb,
                                                     unsigned short* __restrict__ wt){
  int gid = blockIdx.x*256 + threadIdx.x;
  int d   = gid >> 18;
  int rem = gid & 262143;
  int n   = rem >> 8;
  int k   = rem & 255;
  const float* src = d ? Wb : Wf;
  wt[gid] = f2bf_u(src[k*GG + n]);
}

// R [256][1024] f32 -> R^T f16 [dir][1024 col][256 k]
__global__ __launch_bounds__(256) void cvt_rt_kernel(const float* __restrict__ Rf,
                                                     const float* __restrict__ Rb,
                                                     unsigned short* __restrict__ rt){
  int gid = blockIdx.x*256 + threadIdx.x;
  int d   = gid >> 16;
  int rem = gid & 65535;
  int col = rem >> 6;
  int k4  = (rem & 63) << 2;
  const float* src = d ? Rb : Rf;
  unsigned int u0 = (unsigned int)f2h_u(src[(k4+0)*GG + col]) |
                    ((unsigned int)f2h_u(src[(k4+1)*GG + col]) << 16);
  unsigned int u1 = (unsigned int)f2h_u(src[(k4+2)*GG + col]) |
                    ((unsigned int)f2h_u(src[(k4+3)*GG + col]) << 16);
  *(uint2*)(rt + ((size_t)d*1024 + col)*256 + k4) = make_uint2(u0, u1);
}

// ---- proj GEMM: M-tile = 16 batches x 8 timesteps; writes projT[t][col][16b]
__global__ __launch_bounds__(256) void gemm_projT(const unsigned short* __restrict__ Ah,
                                                  const unsigned short* __restrict__ BTh,
                                                  unsigned short* __restrict__ Cd,
                                                  int xstart, int Tc){
  __shared__ __align__(16) unsigned short smem[18432];
  unsigned short* sA = smem;             // [128][72]
  unsigned short* sB = smem + 9216;      // [128][72]
  unsigned short* sC = smem;             // [128][136]

  int mt  = blockIdx.x >> 3;
  int nt  = blockIdx.x & 7;
  int tid = threadIdx.x;

  const unsigned short* Bb = BTh + (size_t)nt*128*DD;

  int w = tid >> 6, lane = tid & 63, l15 = lane & 15, l4 = lane >> 4;
  int wm = w >> 1, wn = w & 1;

  f32x4 zero4 = {0.0f, 0.0f, 0.0f, 0.0f};
  f32x4 acc[4][4];
#pragma unroll
  for (int i = 0; i < 4; ++i)
#pragma unroll
    for (int j = 0; j < 4; ++j) acc[i][j] = zero4;

  for (int kt = 0; kt < 4; ++kt){
    __syncthreads();
#pragma unroll
    for (int i = 0; i < 4; ++i){
      int ch = tid + i*256;
      int r = ch >> 3, c8 = ch & 7;
      int bb = r >> 3, ti = r & 7;
      int tx = xstart + mt*8 + ti;
      *(uint4*)(sA + r*72 + c8*8) = *(const uint4*)(Ah + ((size_t)bb*TT + tx)*DD + kt*64 + c8*8);
      *(uint4*)(sB + r*72 + c8*8) = *(const uint4*)(Bb + (size_t)r*DD + kt*64 + c8*8);
    }
    __syncthreads();
#pragma unroll
    for (int ks = 0; ks < 2; ++ks){
      short8 a[4], b[4];
#pragma unroll
      for (int mf = 0; mf < 4; ++mf)
        a[mf] = *(const short8*)(sA + (wm*64 + mf*16 + l15)*72 + ks*32 + l4*8);
#pragma unroll
      for (int nf = 0; nf < 4; ++nf)
        b[nf] = *(const short8*)(sB + (wn*64 + nf*16 + l15)*72 + ks*32 + l4*8);
#pragma unroll
      for (int mf = 0; mf < 4; ++mf)
#pragma unroll
        for (int nf = 0; nf < 4; ++nf)
          acc[mf][nf] = __builtin_amdgcn_mfma_f32_16x16x32_bf16(a[mf], b[nf], acc[mf][nf], 0, 0, 0);
    }
  }
  __syncthreads();
#pragma unroll
  for (int mf = 0; mf < 4; ++mf)
#pragma unroll
    for (int nf = 0; nf < 4; ++nf)
#pragma unroll
      for (int r = 0; r < 4; ++r)
        sC[(wm*64 + mf*16 + l4*4 + r)*136 + wn*64 + nf*16 + l15] = f2h_u(acc[mf][nf][r]);
  __syncthreads();
  int c = tid >> 1, half = tid & 1;
#pragma unroll
  for (int ti = 0; ti < 8; ++ti){
    unsigned short* slab = Cd + ((size_t)(mt*8 + ti)*GG + nt*128)*16;
    unsigned short v[8];
#pragma unroll
    for (int j = 0; j < 8; ++j)
      v[j] = sC[((half*8 + j)*8 + ti)*136 + c];
    uint4 pk;
    pk.x = (unsigned int)v[0] | ((unsigned int)v[1] << 16);
    pk.y = (unsigned int)v[2] | ((unsigned int)v[3] << 16);
    pk.z = (unsigned int)v[4] | ((unsigned int)v[5] << 16);
    pk.w = (unsigned int)v[6] | ((unsigned int)v[7] << 16);
    *(uint4*)(slab + c*16 + half*8) = pk;
  }
}

// ---- MFMA LSTM scan: 8 blocks/dir, 32 units each, all-to-all h exchange ---
// Wave w: gate g=w>>1, k-half kh=w&1 (k slices 4kh..4kh+3), both 16-unit tiles.
// B-frags: 8 per wave = 32 VGPR, register-resident (pinned).
// Partial sums (2 k-halves) combined via gx LDS; epilogue: 256 thr x 2 states.
__global__ __attribute__((amdgpu_flat_work_group_size(512, 512), amdgpu_waves_per_eu(2, 2)))
void lstm_scan_mfma(const unsigned short* __restrict__ projT,  // [2][Tc][1024][16] f16
                    const unsigned short* __restrict__ Rt,     // [2][1024][256] f16
                    const float* __restrict__ bcf, const float* __restrict__ bcb,
                    float* __restrict__ out,
                    float* __restrict__ stH, float* __restrict__ stC,
                    unsigned int* __restrict__ xchg,           // [2 d][2 slot][8 Q][8 bp][32 u]
                    int* __restrict__ flags,                   // [16][32] int
                    int t0, int t1, int Tc, int first)
{
  __shared__ __align__(16) unsigned short h_lds[16][264];  // 8448 B  [batch][unit]
  __shared__ float gx[2][4][32][17];                       // 17408 B [kh][gate][unit][batch]

  int blk = blockIdx.x;
  int d = blk & 7, Q = blk >> 3;
  if (d >= 2) return;

  int tid = threadIdx.x;
  int w = tid >> 6, l = tid & 63, l15 = l & 15, l4 = l >> 4;
  int g = w >> 1, kh = w & 1;
  int ub = Q*32;

  // ---- stage B-fragments: frag[uh][j] for k slice 4kh+j, unit tile uh ----
  u32x4 frag[2][4];
  {
    const unsigned short* Rd = Rt + (size_t)d*262144;
#pragma unroll
    for (int uh = 0; uh < 2; ++uh){
      const unsigned short* colp = Rd + (size_t)(g*256 + ub + uh*16 + l15)*256 + kh*128 + l4*8;
#pragma unroll
      for (int j = 0; j < 4; ++j)
        frag[uh][j] = *(const u32x4*)(colp + j*32);
    }
  }
#pragma unroll
  for (int uh = 0; uh < 2; ++uh)
#pragma unroll
    for (int j = 0; j < 4; ++j)
      asm volatile("" : "+v"(frag[uh][j]));   // block remat/spill (32 VGPR total)

  // ---- init h_lds (full 256 units x 16 batches) ----
  const float* stHb = stH + d*4096;
  for (int idx = tid; idx < 4096; idx += 512){
    int row = idx >> 8, col = idx & 255;
    h_lds[row][col] = first ? (unsigned short)0 : f2h_u(stHb[idx]);
  }

  // ---- epilogue thread state: (unit u_e, batches 2bp, 2bp+1) ----
  int u_e = tid & 31, bp = tid >> 5;          // valid for tid<256
  int ugE = ub + u_e;
  float c0 = 0.f, c1 = 0.f, h0s = 0.f, h1s = 0.f, bc_r = 0.f;
  if (tid < 256){
    if (!first){
      c0 = stC[(d*16 + 2*bp    )*256 + ugE];
      c1 = stC[(d*16 + 2*bp + 1)*256 + ugE];
    }
    bc_r = (d ? bcb : bcf)[ugE];
  }

  const unsigned short* prj = projT + (size_t)d*Tc*16384;
  const int myflag = (d*8 + Q)*32;
  const int p = (Q + 1 + w) & 7;              // partner for import waves 0..6
  const int paflag = (d*8 + p)*32;
  unsigned long long* xb = (unsigned long long*)xchg;
  float* outb = out + d*256 + ugE;
  const int Tl = t1 - t0;

  __syncthreads();

  for (int s = 0; s < Tl; ++s){
    int t = t0 + s;
    int ps = d ? (Tl - 1 - s) : s;

    // ---- proj loads (epilogue threads), issued early ----
    unsigned int pjg[4] = {0,0,0,0};
    if (tid < 256){
      const unsigned short* pr = prj + (size_t)ps*16384;
#pragma unroll
      for (int gg = 0; gg < 4; ++gg)
        pjg[gg] = *(const unsigned int*)(pr + (gg*256 + ugE)*16 + 2*bp);
    }

    // ---- import partner h (waves 0..6): poll flag, 16B L2 load, land b64 --
    if (s > 0 && w < 7){
      while (__hip_atomic_load(&flags[paflag], __ATOMIC_RELAXED, __HIP_MEMORY_SCOPE_AGENT) < s)
        __builtin_amdgcn_s_sleep(1);
      size_t base = (((size_t)d*2 + ((s - 1) & 1))*8 + p)*128;
      unsigned long long v0 = __hip_atomic_load(&xb[base + 2*l    ], __ATOMIC_RELAXED, __HIP_MEMORY_SCOPE_AGENT);
      unsigned long long v1 = __hip_atomic_load(&xb[base + 2*l + 1], __ATOMIC_RELAXED, __HIP_MEMORY_SCOPE_AGENT);
      unsigned int uA = (unsigned int)v0, uB = (unsigned int)(v0 >> 32);
      unsigned int uC = (unsigned int)v1, uD = (unsigned int)(v1 >> 32);
      unsigned int lo0 = (uA & 0xffffu) | (uB << 16);
      unsigned int lo1 = (uC & 0xffffu) | (uD << 16);
      unsigned int hi0 = (uA >> 16) | (uB & 0xffff0000u);
      unsigned int hi1 = (uC >> 16) | (uD & 0xffff0000u);
      int bpi = l >> 3, u0i = 32*p + 4*(l & 7);
      *(uint2*)&h_lds[2*bpi    ][u0i] = make_uint2(lo0, lo1);
      *(uint2*)&h_lds[2*bpi + 1][u0i] = make_uint2(hi0, hi1);
    }
    __syncthreads();                          // B1: imports + own h visible

    // ---- MFMA: gate g, k slices 4kh..4kh+3, both unit tiles ----
    f32x4 acc0 = {0.f,0.f,0.f,0.f}, acc1 = acc0;
#pragma unroll
    for (int j = 0; j < 4; ++j){
      f16x8 af = *(const f16x8*)&h_lds[l15][(4*kh + j)*32 + l4*8];
      acc0 = mfma16x16x32_f16(af, __builtin_bit_cast(f16x8, frag[0][j]), acc0);
      acc1 = mfma16x16x32_f16(af, __builtin_bit_cast(f16x8, frag[1][j]), acc1);
    }
    // partial sums -> gx[kh][g][unit][batch]
#pragma unroll
    for (int r = 0; r < 4; ++r){
      gx[kh][g][l15     ][l4*4 + r] = acc0[r];
      gx[kh][g][16 + l15][l4*4 + r] = acc1[r];
    }
    __syncthreads();                          // B2: gx visible

    // ---- epilogue: 256 threads, 2 states each ----
    if (tid < 256){
      float ga0[4], ga1[4];
#pragma unroll
      for (int gg = 0; gg < 4; ++gg){
        ga0[gg] = gx[0][gg][u_e][2*bp]     + gx[1][gg][u_e][2*bp]
                + h2f((unsigned short)pjg[gg]);
        ga1[gg] = gx[0][gg][u_e][2*bp + 1] + gx[1][gg][u_e][2*bp + 1]
                + h2f((unsigned short)(pjg[gg] >> 16));
      }
      float ig0 = sigmoid_f(ga0[0]), fg0 = sigmoid_f(ga0[1]), og0 = sigmoid_f(ga0[2]);
      float ig1 = sigmoid_f(ga1[0]), fg1 = sigmoid_f(ga1[1]), og1 = sigmoid_f(ga1[2]);
      float cd0 = tanh_f(ga0[3] + bc_r), cd1 = tanh_f(ga1[3] + bc_r);
      c0 = sigmoid_f(fg0*c0 + ig0*cd0);       // faithful quirk
      c1 = sigmoid_f(fg1*c1 + ig1*cd1);
      float h0 = tanh_f(c0) * og0;            // faithful quirk
      float h1 = tanh_f(c1) * og1;
      h0s = h0; h1s = h1;

      unsigned short hu0 = f2h_u(h0), hu1 = f2h_u(h1);
      h_lds[2*bp    ][ugE] = hu0;             // own units, read next step
      h_lds[2*bp + 1][ugE] = hu1;
      // export: coalesced 1 uint/thread
      __hip_atomic_store(&xchg[(((size_t)d*2 + (s & 1))*8 + Q)*256 + tid],
                         (unsigned int)hu0 | ((unsigned int)hu1 << 16),
                         __ATOMIC_RELAXED, __HIP_MEMORY_SCOPE_AGENT);
      outb[((size_t)(2*bp    )*TT + t)*512] = h0;
      outb[((size_t)(2*bp + 1)*TT + t)*512] = h1;
    }
    asm volatile("s_waitcnt vmcnt(0)" ::: "memory");  // exports at coherence point
    __syncthreads();                          // B3: all waves drained, h_lds visible
    if (tid == 0)
      __hip_atomic_store(&flags[myflag], s + 1, __ATOMIC_RELAXED, __HIP_MEMORY_SCOPE_AGENT);
  }

  // chunk-carry state
  if (tid < 256){
    stC[(d*16 + 2*bp    )*256 + ugE] = c0;
    stC[(d*16 + 2*bp + 1)*256 + ugE] = c1;
    stH[(d*16 + 2*bp    )*256 + ugE] = h0s;
    stH[(d*16 + 2*bp + 1)*256 + ugE] = h1s;
  }
}

// ---- launcher -------------------------------------------------------------
extern "C" void kernel_launch(void* const* d_in, const int* in_sizes, int n_in,
                              void* d_out, int out_size, void* d_ws, size_t ws_size,
                              hipStream_t stream){
  const float* x   = (const float*)d_in[0];
  const float* Wf  = (const float*)d_in[1];
  const float* Rf  = (const float*)d_in[2];
  const float* bcf = (const float*)d_in[3];
  const float* Wb  = (const float*)d_in[4];
  const float* Rb  = (const float*)d_in[5];
  const float* bcb = (const float*)d_in[6];
  float* out = (float*)d_out;
  char* ws = (char*)d_ws;

  const size_t OFF_XH    = 0;                        // 16 MiB: x bf16
  const size_t OFF_WT    = 16777216;                 // 1 MiB: W^T bf16 both dirs
  const size_t OFF_RT    = OFF_WT + 1048576;         // 1 MiB: R^T f16 both dirs
  const size_t OFF_STH   = OFF_RT + 1048576;         // 32 KiB h state
  const size_t OFF_STC   = OFF_STH + 32768;          // 32 KiB c state
  const size_t OFF_XCHG  = OFF_STC + 32768;          // 32 KiB h exchange (2*2*8*256*4)
  const size_t OFF_FLAGS = OFF_XCHG + 65536;         // 4 KiB flags
  const size_t OFF_PROJT = OFF_FLAGS + 4096;         // projT chunk buffer

  unsigned short* xh    = (unsigned short*)(ws + OFF_XH);
  unsigned short* wt    = (unsigned short*)(ws + OFF_WT);
  unsigned short* rt    = (unsigned short*)(ws + OFF_RT);
  float*          stH   = (float*)(ws + OFF_STH);
  float*          stC   = (float*)(ws + OFF_STC);
  unsigned int*   xchg  = (unsigned int*)(ws + OFF_XCHG);
  int*            flags = (int*)(ws + OFF_FLAGS);
  unsigned short* projT = (unsigned short*)(ws + OFF_PROJT);

  int Tc = TT;  // time-chunk; shrink if ws too small (projT = 65536*Tc bytes)
  while (Tc > 128 && OFF_PROJT + (size_t)65536*Tc > ws_size) Tc >>= 1;

  cvt_x_kernel<<<8192, 256, 0, stream>>>(x, xh);
  cvt_wt_kernel<<<2048, 256, 0, stream>>>(Wf, Wb, wt);
  cvt_rt_kernel<<<512, 256, 0, stream>>>(Rf, Rb, rt);

  int nch = TT / Tc;
  for (int ch = 0; ch < nch; ++ch){
    int t0 = ch*Tc, t1 = t0 + Tc;
    gemm_projT<<<Tc, 256, 0, stream>>>(xh, wt,          projT,                     t0,      Tc);
    gemm_projT<<<Tc, 256, 0, stream>>>(xh, wt + 262144, projT + (size_t)Tc*GG*16,  TT - t1, Tc);
    hipMemsetAsync(flags, 0, 2048, stream);
    lstm_scan_mfma<<<64, 512, 0, stream>>>(projT, rt, bcf, bcb, out, stH, stC, xchg, flags,
                                           t0, t1, Tc, ch == 0 ? 1 : 0);
  }
}

// Round 8
// 3805.883 us; speedup vs baseline: 2.5380x; 1.1551x over previous
//
#include <hip/hip_runtime.h>
#include <hip/hip_bf16.h>
#include <hip/hip_fp16.h>

#define TT 2048
#define BB 16
#define DD 256
#define GG 1024   // 4U
#define UU 256

using f32x4  = __attribute__((ext_vector_type(4))) float;
using short8 = __attribute__((ext_vector_type(8))) short;
using f16x8  = __attribute__((ext_vector_type(8))) _Float16;
using u32x4  = __attribute__((ext_vector_type(4))) unsigned int;

static __device__ __forceinline__ unsigned short f2h_u(float f){
  _Float16 h = (_Float16)f;
  return __builtin_bit_cast(unsigned short, h);
}
static __device__ __forceinline__ float h2f(unsigned short u){
  return (float)__builtin_bit_cast(_Float16, u);
}
static __device__ __forceinline__ unsigned short f2bf_u(float f){
  __hip_bfloat16 b = __float2bfloat16(f);
  return __builtin_bit_cast(unsigned short, b);
}
static __device__ __forceinline__ float sigmoid_f(float x){
  return 1.0f / (1.0f + __expf(-x));
}
static __device__ __forceinline__ float tanh_f(float x){
  float ax = fabsf(x);
  float e  = __expf(2.0f*ax);          // overflow -> inf is fine: r -> 1
  float r  = 1.0f - 2.0f/(e + 1.0f);
  return copysignf(r, x);
}
static __device__ __forceinline__ f32x4 mfma16x16x32_f16(f16x8 a, f16x8 b, f32x4 c){
  return __builtin_amdgcn_mfma_f32_16x16x32_f16(a, b, c, 0, 0, 0);
}

// ---- converts -------------------------------------------------------------
__global__ __launch_bounds__(256) void cvt_x_kernel(const float* __restrict__ x,
                                                    unsigned short* __restrict__ xh){
  int gid = blockIdx.x*256 + threadIdx.x;
  const float4* xv = (const float4*)x;
  float4 v = xv[gid];
  unsigned int u0 = (unsigned int)f2bf_u(v.x) | ((unsigned int)f2bf_u(v.y) << 16);
  unsigned int u1 = (unsigned int)f2bf_u(v.z) | ((unsigned int)f2bf_u(v.w) << 16);
  ((uint2*)xh)[gid] = make_uint2(u0, u1);
}

// W [256][1024] f32 -> W^T bf16 [dir][1024][256]
__global__ __launch_bounds__(256) void cvt_wt_kernel(const float* __restrict__ Wf,
                                                     const float* __restrict__ Wb,
                                                     unsigned short* __restrict__ wt){
  int gid = blockIdx.x*256 + threadIdx.x;
  int d   = gid >> 18;
  int rem = gid & 262143;
  int n   = rem >> 8;
  int k   = rem & 255;
  const float* src = d ? Wb : Wf;
  wt[gid] = f2bf_u(src[k*GG + n]);
}

// R [256][1024] f32 -> A-fragment-ready f16, col-order [block Q][unit][gate],
// k-permuted to match the scan's h^T B-fragment assembly:
//   storage pos p (0..255): s=p>>5, l4=(p>>3)&3, e=p&7
//   k = 32s + (e<4 ? 4*l4+e : 16 + 4*l4 + (e-4))
__global__ __launch_bounds__(256) void cvt_rt_kernel(const float* __restrict__ Rf,
                                                     const float* __restrict__ Rb,
                                                     unsigned short* __restrict__ rt){
  int gid = blockIdx.x*256 + threadIdx.x;           // 2*1024*256
  int d   = gid >> 18;
  int rem = gid & 262143;
  int c   = rem >> 8;                               // storage col 0..1023
  int p   = rem & 255;                              // k-position
  int Qb  = c >> 7, tc = c & 127;
  int ul  = tc >> 2, g = tc & 3;
  int ucol = g*256 + Qb*32 + ul;                    // source col in R[256][1024]
  int s = p >> 5, l4g = (p >> 3) & 3, e = p & 7;
  int k = 32*s + (e < 4 ? 4*l4g + e : 16 + 4*l4g + (e - 4));
  const float* src = d ? Rb : Rf;
  rt[gid] = f2h_u(src[k*GG + ucol]);
}

// ---- proj GEMM: M-tile = 16 batches x 8 timesteps; writes projT[t][col][16b]
__global__ __launch_bounds__(256) void gemm_projT(const unsigned short* __restrict__ Ah,
                                                  const unsigned short* __restrict__ BTh,
                                                  unsigned short* __restrict__ Cd,
                                                  int xstart, int Tc){
  __shared__ __align__(16) unsigned short smem[18432];
  unsigned short* sA = smem;             // [128][72]
  unsigned short* sB = smem + 9216;      // [128][72]
  unsigned short* sC = smem;             // [128][136]

  int mt  = blockIdx.x >> 3;
  int nt  = blockIdx.x & 7;
  int tid = threadIdx.x;

  const unsigned short* Bb = BTh + (size_t)nt*128*DD;

  int w = tid >> 6, lane = tid & 63, l15 = lane & 15, l4 = lane >> 4;
  int wm = w >> 1, wn = w & 1;

  f32x4 zero4 = {0.0f, 0.0f, 0.0f, 0.0f};
  f32x4 acc[4][4];
#pragma unroll
  for (int i = 0; i < 4; ++i)
#pragma unroll
    for (int j = 0; j < 4; ++j) acc[i][j] = zero4;

  for (int kt = 0; kt < 4; ++kt){
    __syncthreads();
#pragma unroll
    for (int i = 0; i < 4; ++i){
      int ch = tid + i*256;
      int r = ch >> 3, c8 = ch & 7;
      int bb = r >> 3, ti = r & 7;
      int tx = xstart + mt*8 + ti;
      *(uint4*)(sA + r*72 + c8*8) = *(const uint4*)(Ah + ((size_t)bb*TT + tx)*DD + kt*64 + c8*8);
      *(uint4*)(sB + r*72 + c8*8) = *(const uint4*)(Bb + (size_t)r*DD + kt*64 + c8*8);
    }
    __syncthreads();
#pragma unroll
    for (int ks = 0; ks < 2; ++ks){
      short8 a[4], b[4];
#pragma unroll
      for (int mf = 0; mf < 4; ++mf)
        a[mf] = *(const short8*)(sA + (wm*64 + mf*16 + l15)*72 + ks*32 + l4*8);
#pragma unroll
      for (int nf = 0; nf < 4; ++nf)
        b[nf] = *(const short8*)(sB + (wn*64 + nf*16 + l15)*72 + ks*32 + l4*8);
#pragma unroll
      for (int mf = 0; mf < 4; ++mf)
#pragma unroll
        for (int nf = 0; nf < 4; ++nf)
          acc[mf][nf] = __builtin_amdgcn_mfma_f32_16x16x32_bf16(a[mf], b[nf], acc[mf][nf], 0, 0, 0);
    }
  }
  __syncthreads();
#pragma unroll
  for (int mf = 0; mf < 4; ++mf)
#pragma unroll
    for (int nf = 0; nf < 4; ++nf)
#pragma unroll
      for (int r = 0; r < 4; ++r)
        sC[(wm*64 + mf*16 + l4*4 + r)*136 + wn*64 + nf*16 + l15] = f2h_u(acc[mf][nf][r]);
  __syncthreads();
  int c = tid >> 1, half = tid & 1;
#pragma unroll
  for (int ti = 0; ti < 8; ++ti){
    unsigned short* slab = Cd + ((size_t)(mt*8 + ti)*GG + nt*128)*16;
    unsigned short v[8];
#pragma unroll
    for (int j = 0; j < 8; ++j)
      v[j] = sC[((half*8 + j)*8 + ti)*136 + c];
    uint4 pk;
    pk.x = (unsigned int)v[0] | ((unsigned int)v[1] << 16);
    pk.y = (unsigned int)v[2] | ((unsigned int)v[3] << 16);
    pk.z = (unsigned int)v[4] | ((unsigned int)v[5] << 16);
    pk.w = (unsigned int)v[6] | ((unsigned int)v[7] << 16);
    *(uint4*)(slab + c*16 + half*8) = pk;
  }
}

// ---- MFMA LSTM scan: A=R(regs), B=h(LDS), lane-local epilogue --------------
// 8 blocks/dir (32 units each). Wave w = M-tile (units 4w..4w+3 x 4 gates).
// h^T LDS layout: hT[uq 64][batch 17-pad][4 units] shorts (68 shorts/uq row).
// Lane (l15=batch, l4): acc[r] = gate r of unit 4w+l4, batch l15.
template<int Q>
__device__ __forceinline__ void scan_body(
    unsigned short* hT,                        // [64*68] shorts
    const unsigned short* __restrict__ projT,  // [2][Tc][1024][16] f16
    const unsigned short* __restrict__ rt,     // [2][1024][256] f16 (permuted)
    const float* __restrict__ bcf, const float* __restrict__ bcb,
    float* __restrict__ out,
    float* __restrict__ stH, float* __restrict__ stC,
    unsigned short* __restrict__ xchg,         // [2 d][2 slot][8 Q][512] shorts
    int* __restrict__ flags,                   // [16][32] int
    int t0, int t1, int Tc, int first, int d)
{
  int tid = threadIdx.x;
  int w = tid >> 6, l = tid & 63, l15 = l & 15, l4 = l >> 4;

  // ---- A-fragments (R), 8 slices x b128 = 32 VGPR, register-pinned ----
  u32x4 frag[8];
  {
    const unsigned short* Rd = rt + (size_t)d*262144
                             + ((size_t)(Q*128 + w*16 + l15))*256 + l4*8;
#pragma unroll
    for (int s = 0; s < 8; ++s)
      frag[s] = *(const u32x4*)(Rd + s*32);
  }
#pragma unroll
  for (int s = 0; s < 8; ++s)
    asm volatile("" : "+v"(frag[s]));

  // ---- init hT (all 256 units x 16 batches) ----
  const float* stHb = stH + d*4096;
  for (int idx = tid; idx < 4096; idx += 512){
    int b = idx >> 8, u = idx & 255;
    hT[(u >> 2)*68 + b*4 + (u & 3)] = first ? (unsigned short)0
                                            : f2h_u(stHb[b*256 + u]);
  }

  const int u_loc = 4*w + l4, u_g = 32*Q + u_loc;
  float c_r = 0.f, h_r = 0.f;
  if (!first) c_r = stC[(d*16 + l15)*256 + u_g];
  float bc_r = (d ? bcb : bcf)[u_g];

  const unsigned short* prj = projT + (size_t)d*Tc*16384;
  const int myflag = (d*8 + Q)*32;
  const int p = (Q + w) & 7;                  // import partner (waves 1..7)
  const int paflag = (d*8 + p)*32;
  const unsigned long long* xull = (const unsigned long long*)xchg;
  const int Tl = t1 - t0;

  __syncthreads();

  for (int s = 0; s < Tl; ++s){
    int t = t0 + s;
    int ps = d ? (Tl - 1 - s) : s;

    // proj: 4 b16 loads (consumed in epilogue; latency hidden)
    const unsigned short* pr = prj + (size_t)ps*16384;
    unsigned short pj0 = pr[(0*256 + u_g)*16 + l15];
    unsigned short pj1 = pr[(1*256 + u_g)*16 + l15];
    unsigned short pj2 = pr[(2*256 + u_g)*16 + l15];
    unsigned short pj3 = pr[(3*256 + u_g)*16 + l15];

    // import partner slab (waves 1..7): poll + 2 ull atomic loads
    unsigned long long v0 = 0, v1 = 0;
    if (s > 0 && w >= 1){
      while (__hip_atomic_load(&flags[paflag], __ATOMIC_RELAXED, __HIP_MEMORY_SCOPE_AGENT) < s)
        __builtin_amdgcn_s_sleep(1);
      size_t base = (((size_t)d*2 + ((s - 1) & 1))*8 + p)*128;
      v0 = __hip_atomic_load(&xull[base + 2*l    ], __ATOMIC_RELAXED, __HIP_MEMORY_SCOPE_AGENT);
      v1 = __hip_atomic_load(&xull[base + 2*l + 1], __ATOMIC_RELAXED, __HIP_MEMORY_SCOPE_AGENT);
    }

    // own slice (units 32Q..32Q+31, written locally last step) before B1
    f32x4 acc = {0.f, 0.f, 0.f, 0.f};
    {
      uint2 b0 = *(const uint2*)&hT[(Q*8     + l4)*68 + l15*4];
      uint2 b1 = *(const uint2*)&hT[(Q*8 + 4 + l4)*68 + l15*4];
      u32x4 bv = {b0.x, b0.y, b1.x, b1.y};
      acc = mfma16x16x32_f16(__builtin_bit_cast(f16x8, frag[Q]),
                             __builtin_bit_cast(f16x8, bv), acc);
    }

    // land imports (contiguous 2 x b64 per lane)
    if (s > 0 && w >= 1){
      int uq = 8*p + (l >> 3), bq = 2*(l & 7);
      *(uint2*)&hT[uq*68 + bq*4    ] = make_uint2((unsigned)v0, (unsigned)(v0 >> 32));
      *(uint2*)&hT[uq*68 + bq*4 + 4] = make_uint2((unsigned)v1, (unsigned)(v1 >> 32));
    }
    __syncthreads();                          // B1: imports visible

    // remaining 7 slices (compile-time frag index via template Q)
#pragma unroll
    for (int j = 1; j < 8; ++j){
      const int sg = (Q + j) & 7;
      uint2 b0 = *(const uint2*)&hT[(sg*8     + l4)*68 + l15*4];
      uint2 b1 = *(const uint2*)&hT[(sg*8 + 4 + l4)*68 + l15*4];
      u32x4 bv = {b0.x, b0.y, b1.x, b1.y};
      acc = mfma16x16x32_f16(__builtin_bit_cast(f16x8, frag[sg]),
                             __builtin_bit_cast(f16x8, bv), acc);
    }
    __syncthreads();                          // B2: all hT reads done

    // ---- lane-local epilogue: 1 state (unit u_g, batch l15) ----
    float gi = acc[0] + h2f(pj0);
    float gf = acc[1] + h2f(pj1);
    float go = acc[2] + h2f(pj2);
    float gc = acc[3] + h2f(pj3) + bc_r;
    float ig = sigmoid_f(gi);
    float fg = sigmoid_f(gf);
    float og = sigmoid_f(go);
    float cand = tanh_f(gc);
    c_r = sigmoid_f(fg*c_r + ig*cand);        // faithful quirk
    float h = tanh_f(c_r) * og;               // faithful quirk
    h_r = h;

    unsigned short hu = f2h_u(h);
    hT[(8*Q + w)*68 + l15*4 + l4] = hu;       // own region, read next step
    xchg[((size_t)(d*2 + (s & 1))*8 + Q)*512 + w*64 + l15*4 + l4] = hu;
    asm volatile("s_waitcnt vmcnt(0)" ::: "memory");  // export visible at L2
    __syncthreads();                          // B3: hT writes + all exports
    if (tid == 0)
      __hip_atomic_store(&flags[myflag], s + 1, __ATOMIC_RELAXED, __HIP_MEMORY_SCOPE_AGENT);
    // out store after flag: its latency overlaps next step's poll
    out[((size_t)l15*TT + t)*512 + d*256 + u_g] = h;
  }

  // chunk-carry state
  stC[(d*16 + l15)*256 + u_g] = c_r;
  stH[(d*16 + l15)*256 + u_g] = h_r;
}

__global__ __attribute__((amdgpu_flat_work_group_size(512, 512), amdgpu_waves_per_eu(2, 2)))
void lstm_scan_mfma(const unsigned short* __restrict__ projT,
                    const unsigned short* __restrict__ rt,
                    const float* __restrict__ bcf, const float* __restrict__ bcb,
                    float* __restrict__ out,
                    float* __restrict__ stH, float* __restrict__ stC,
                    unsigned short* __restrict__ xchg,
                    int* __restrict__ flags,
                    int t0, int t1, int Tc, int first)
{
  __shared__ __align__(16) unsigned short hT[64*68];   // 8704 B
  int blk = blockIdx.x;
  int d = blk & 7, Q = blk >> 3;                       // dir d pinned to XCD d
  if (d >= 2) return;
  switch (Q){
    case 0: scan_body<0>(hT, projT, rt, bcf, bcb, out, stH, stC, xchg, flags, t0, t1, Tc, first, d); break;
    case 1: scan_body<1>(hT, projT, rt, bcf, bcb, out, stH, stC, xchg, flags, t0, t1, Tc, first, d); break;
    case 2: scan_body<2>(hT, projT, rt, bcf, bcb, out, stH, stC, xchg, flags, t0, t1, Tc, first, d); break;
    case 3: scan_body<3>(hT, projT, rt, bcf, bcb, out, stH, stC, xchg, flags, t0, t1, Tc, first, d); break;
    case 4: scan_body<4>(hT, projT, rt, bcf, bcb, out, stH, stC, xchg, flags, t0, t1, Tc, first, d); break;
    case 5: scan_body<5>(hT, projT, rt, bcf, bcb, out, stH, stC, xchg, flags, t0, t1, Tc, first, d); break;
    case 6: scan_body<6>(hT, projT, rt, bcf, bcb, out, stH, stC, xchg, flags, t0, t1, Tc, first, d); break;
    default: scan_body<7>(hT, projT, rt, bcf, bcb, out, stH, stC, xchg, flags, t0, t1, Tc, first, d); break;
  }
}

// ---- launcher -------------------------------------------------------------
extern "C" void kernel_launch(void* const* d_in, const int* in_sizes, int n_in,
                              void* d_out, int out_size, void* d_ws, size_t ws_size,
                              hipStream_t stream){
  const float* x   = (const float*)d_in[0];
  const float* Wf  = (const float*)d_in[1];
  const float* Rf  = (const float*)d_in[2];
  const float* bcf = (const float*)d_in[3];
  const float* Wb  = (const float*)d_in[4];
  const float* Rb  = (const float*)d_in[5];
  const float* bcb = (const float*)d_in[6];
  float* out = (float*)d_out;
  char* ws = (char*)d_ws;

  const size_t OFF_XH    = 0;                        // 16 MiB: x bf16
  const size_t OFF_WT    = 16777216;                 // 1 MiB: W^T bf16 both dirs
  const size_t OFF_RT    = OFF_WT + 1048576;         // 1 MiB: R frags f16 both dirs
  const size_t OFF_STH   = OFF_RT + 1048576;         // 32 KiB h state
  const size_t OFF_STC   = OFF_STH + 32768;          // 32 KiB c state
  const size_t OFF_XCHG  = OFF_STC + 32768;          // 32 KiB h exchange
  const size_t OFF_FLAGS = OFF_XCHG + 32768;         // 4 KiB flags
  const size_t OFF_PROJT = OFF_FLAGS + 4096;         // projT chunk buffer

  unsigned short* xh    = (unsigned short*)(ws + OFF_XH);
  unsigned short* wt    = (unsigned short*)(ws + OFF_WT);
  unsigned short* rt    = (unsigned short*)(ws + OFF_RT);
  float*          stH   = (float*)(ws + OFF_STH);
  float*          stC   = (float*)(ws + OFF_STC);
  unsigned short* xchg  = (unsigned short*)(ws + OFF_XCHG);
  int*            flags = (int*)(ws + OFF_FLAGS);
  unsigned short* projT = (unsigned short*)(ws + OFF_PROJT);

  int Tc = TT;  // time-chunk; shrink if ws too small (projT = 65536*Tc bytes)
  while (Tc > 128 && OFF_PROJT + (size_t)65536*Tc > ws_size) Tc >>= 1;

  cvt_x_kernel<<<8192, 256, 0, stream>>>(x, xh);
  cvt_wt_kernel<<<2048, 256, 0, stream>>>(Wf, Wb, wt);
  cvt_rt_kernel<<<2048, 256, 0, stream>>>(Rf, Rb, rt);

  int nch = TT / Tc;
  for (int ch = 0; ch < nch; ++ch){
    int t0 = ch*Tc, t1 = t0 + Tc;
    gemm_projT<<<Tc, 256, 0, stream>>>(xh, wt,          projT,                     t0,      Tc);
    gemm_projT<<<Tc, 256, 0, stream>>>(xh, wt + 262144, projT + (size_t)Tc*GG*16,  TT - t1, Tc);
    hipMemsetAsync(flags, 0, 2048, stream);
    lstm_scan_mfma<<<64, 512, 0, stream>>>(projT, rt, bcf, bcb, out, stH, stC, xchg, flags,
                                           t0, t1, Tc, ch == 0 ? 1 : 0);
  }
}